// Round 5
// baseline (165.096 us; speedup 1.0000x reference)
//
#include <hip/hip_runtime.h>
#include <hip/hip_cooperative_groups.h>
#include <math.h>

namespace cg = cooperative_groups;

#define KW_ELEMS 294912   // 3*3*128*256
#define LR_GD 0.01

typedef __attribute__((ext_vector_type(8))) short short8;
typedef __attribute__((ext_vector_type(4))) float f32x4;

// ws layout (bytes):
//   0   : double sum_w
//   8   : double sum_w2
//   16  : int    Gint[15]
//   80  : double c5[5]
//   128 : float  alphas[5]
//   160 : ushort W_packed[9][256][128]   (bf16, [tap][cout][cin])
#define WS_GINT_OFF  16
#define WS_C5_OFF    80
#define WS_ALPHA_OFF 128
#define WS_WP_OFF    160

__device__ __forceinline__ unsigned short f2bf(float f) {
    union { float f; unsigned int u; } v; v.f = f;
    unsigned int r = v.u + 0x7fffu + ((v.u >> 16) & 1u);   // RNE
    return (unsigned short)(r >> 16);
}

// ---------------- closed-form 500-step GD (1 thread, f64) --------------------
__device__ __forceinline__ void mm5(double* __restrict__ D,
                                    const double* __restrict__ X,
                                    const double* __restrict__ Y) {
    #pragma unroll
    for (int i = 0; i < 5; i++) {
        #pragma unroll
        for (int j = 0; j < 5; j++) {
            double s = 0.0;
            #pragma unroll
            for (int k = 0; k < 5; k++) s += X[i * 5 + k] * Y[k * 5 + j];
            D[i * 5 + j] = s;
        }
    }
}

__device__ void compute_alphas(const int* gw, const double* cw,
                               const float* a0f, float* alph_out) {
    double G[25], C[5];
    {
        int t = 0;
        #pragma unroll
        for (int i = 0; i < 5; i++) {
            #pragma unroll
            for (int j = i; j < 5; j++) {
                double v = (double)gw[t] / (double)KW_ELEMS; t++;
                G[i * 5 + j] = v; G[j * 5 + i] = v;
            }
        }
    }
    #pragma unroll
    for (int i = 0; i < 5; i++) C[i] = cw[i] / (double)KW_ELEMS;

    double L[25];
    #pragma unroll
    for (int i = 0; i < 25; i++) L[i] = 0.0;
    #pragma unroll
    for (int i = 0; i < 5; i++) {
        #pragma unroll
        for (int j = 0; j <= i; j++) {
            double s = G[i * 5 + j];
            #pragma unroll
            for (int k = 0; k < j; k++) s -= L[i * 5 + k] * L[j * 5 + k];
            if (i == j) L[i * 5 + j] = sqrt(s);
            else        L[i * 5 + j] = s / L[j * 5 + j];
        }
    }
    double y[5], astar[5];
    #pragma unroll
    for (int i = 0; i < 5; i++) {
        double s = C[i];
        #pragma unroll
        for (int k = 0; k < i; k++) s -= L[i * 5 + k] * y[k];
        y[i] = s / L[i * 5 + i];
    }
    #pragma unroll
    for (int ii = 0; ii < 5; ii++) {
        int i = 4 - ii;
        double s = y[i];
        #pragma unroll
        for (int k = 0; k < 5; k++) if (k > i) s -= L[k * 5 + i] * astar[k];
        astar[i] = s / L[i * 5 + i];
    }
    double A[25], R[25], T[25];
    #pragma unroll
    for (int i = 0; i < 25; i++) A[i] = ((i % 6) == 0 ? 1.0 : 0.0) - LR_GD * G[i];
    #pragma unroll
    for (int i = 0; i < 25; i++) R[i] = A[i];
    const int bits[8] = {1, 1, 1, 1, 0, 1, 0, 0};   // 500, square-and-multiply
    for (int s = 0; s < 8; s++) {
        mm5(T, R, R);
        if (bits[s]) { mm5(R, T, A); }
        else {
            #pragma unroll
            for (int i = 0; i < 25; i++) R[i] = T[i];
        }
    }
    double d0[5];
    #pragma unroll
    for (int i = 0; i < 5; i++) d0[i] = (double)a0f[i] - astar[i];
    #pragma unroll
    for (int i = 0; i < 5; i++) {
        double s = astar[i];
        #pragma unroll
        for (int j = 0; j < 5; j++) s += R[i * 5 + j] * d0[j];
        alph_out[i] = (float)s;
    }
}

// ---------------- K_pre: cooperative all-in-one preprocessing ----------------
// grid 256 x 256 threads.
// P1: w stats  -> P2: Gram counts + c  -> P3: alphas (block 0) -> P4: W pack.
__global__ __launch_bounds__(256) void k_pre(const float* __restrict__ w,
                                             const float* __restrict__ a0f,
                                             void* __restrict__ wsv) {
    double* wsd = (double*)wsv;
    int*    gw  = (int*)((char*)wsv + WS_GINT_OFF);
    double* cw  = (double*)((char*)wsv + WS_C5_OFF);
    float*  alp = (float*)((char*)wsv + WS_ALPHA_OFF);
    unsigned short* wp = (unsigned short*)((char*)wsv + WS_WP_OFF);

    __shared__ double s1[256];
    __shared__ double s2[256];
    __shared__ int    lg[4][15];
    __shared__ double lc[4][5];
    __shared__ float  tile[32][64];

    cg::grid_group grid = cg::this_grid();
    int tid  = threadIdx.x;
    int gtid = blockIdx.x * 256 + tid;

    // ---- P1: sum / sumsq (f64) ----
    {
        double a = 0.0, b = 0.0;
        for (int i = gtid; i < KW_ELEMS; i += 256 * 256) {
            double v = (double)w[i];
            a += v; b += v * v;
        }
        s1[tid] = a; s2[tid] = b;
        __syncthreads();
        for (int off = 128; off > 0; off >>= 1) {
            if (tid < off) { s1[tid] += s1[tid + off]; s2[tid] += s2[tid + off]; }
            __syncthreads();
        }
        if (tid == 0) { atomicAdd(&wsd[0], s1[0]); atomicAdd(&wsd[1], s2[0]); }
    }
    grid.sync();

    double mean = wsd[0] / (double)KW_ELEMS;
    double var  = wsd[1] / (double)KW_ELEMS - mean * mean;
    float meanf = (float)mean;
    float sigf  = sqrtf((float)var);

    // ---- P2: G counts (int, exact) + c (f64) ----
    {
        float sh[5];
        #pragma unroll
        for (int m = 0; m < 5; m++) sh[m] = (-1.0f + 0.5f * (float)m) * sigf;
        int g[15]; double c[5];
        #pragma unroll
        for (int t = 0; t < 15; t++) g[t] = 0;
        #pragma unroll
        for (int i = 0; i < 5; i++) c[i] = 0.0;
        for (int idx = gtid; idx < KW_ELEMS; idx += 256 * 256) {
            float wf = w[idx];
            float base = wf - meanf;
            int s[5];
            #pragma unroll
            for (int m = 0; m < 5; m++) {
                float arg = base + sh[m];
                s[m] = (arg > 0.0f) ? 1 : ((arg < 0.0f) ? -1 : 0);
            }
            int t = 0;
            #pragma unroll
            for (int i = 0; i < 5; i++) {
                #pragma unroll
                for (int j = i; j < 5; j++) { g[t] += s[i] * s[j]; t++; }
                c[i] += (double)s[i] * (double)wf;
            }
        }
        #pragma unroll
        for (int t = 0; t < 15; t++) {
            int v = g[t];
            for (int off = 32; off > 0; off >>= 1) v += __shfl_down(v, off, 64);
            g[t] = v;
        }
        #pragma unroll
        for (int i = 0; i < 5; i++) {
            double v = c[i];
            for (int off = 32; off > 0; off >>= 1) v += __shfl_down(v, off, 64);
            c[i] = v;
        }
        int wave = tid >> 6;
        if ((tid & 63) == 0) {
            #pragma unroll
            for (int t = 0; t < 15; t++) lg[wave][t] = g[t];
            #pragma unroll
            for (int i = 0; i < 5; i++) lc[wave][i] = c[i];
        }
        __syncthreads();
        if (tid == 0) {
            #pragma unroll
            for (int t = 0; t < 15; t++)
                atomicAdd(&gw[t], lg[0][t] + lg[1][t] + lg[2][t] + lg[3][t]);
            #pragma unroll
            for (int i = 0; i < 5; i++)
                atomicAdd(&cw[i], lc[0][i] + lc[1][i] + lc[2][i] + lc[3][i]);
        }
    }
    grid.sync();

    // ---- P3: alphas (one thread) ----
    if (blockIdx.x == 0 && tid == 0) compute_alphas(gw, cw, a0f, alp);
    grid.sync();

    // ---- P4: W_packed[tap][cout][cin] bf16, 144 active blocks ----
    if (blockIdx.x < 144) {
        float a0 = alp[0], a1 = alp[1], a2 = alp[2], a3 = alp[3], a4 = alp[4];
        int tap   = blockIdx.x >> 4;
        int rest  = blockIdx.x & 15;
        int cin0  = (rest >> 2) * 32;
        int cout0 = (rest & 3) * 64;

        for (int i = tid; i < 32 * 16; i += 256) {
            int ci = i >> 4;
            int f4 = i & 15;
            float4 v = *(const float4*)(&w[(tap * 128 + cin0 + ci) * 256 + cout0 + f4 * 4]);
            float r[4] = {v.x, v.y, v.z, v.w};
            float al[5] = {a0, a1, a2, a3, a4};
            #pragma unroll
            for (int j = 0; j < 4; j++) {
                float base = r[j] - meanf;
                float acc = 0.0f;
                #pragma unroll
                for (int m = 0; m < 5; m++) {
                    float arg = base + (-1.0f + 0.5f * (float)m) * sigf;
                    float s = (arg > 0.0f) ? 1.0f : ((arg < 0.0f) ? -1.0f : 0.0f);
                    acc += al[m] * s;
                }
                r[j] = acc;
            }
            tile[ci][f4 * 4 + 0] = r[0];
            tile[ci][f4 * 4 + 1] = r[1];
            tile[ci][f4 * 4 + 2] = r[2];
            tile[ci][f4 * 4 + 3] = r[3];
        }
        __syncthreads();

        int cc  = tid & 63;
        int ch8 = tid >> 6;          // 0..3: 8-cin chunk
        unsigned short ob[8];
        #pragma unroll
        for (int k = 0; k < 8; k++) ob[k] = f2bf(tile[ch8 * 8 + k][cc]);
        unsigned short* dst = wp + (tap * 256 + cout0 + cc) * 128 + cin0 + ch8 * 8;
        *(short8*)dst = *(short8*)ob;
    }
}

// ---------------- K_conv: fused binarize-x + 3x3 conv via bf16 MFMA ----------
__device__ __forceinline__ float xeff_one(float xv, float s0, float s1, float s2,
                                          float be0, float be1, float be2) {
    float t0 = fminf(fmaxf(xv + s0, 0.0f), 1.0f) - 0.5f;
    float t1 = fminf(fmaxf(xv + s1, 0.0f), 1.0f) - 0.5f;
    float t2 = fminf(fmaxf(xv + s2, 0.0f), 1.0f) - 0.5f;
    float g0 = (t0 > 0.0f) ? 1.0f : ((t0 < 0.0f) ? -1.0f : 0.0f);
    float g1 = (t1 > 0.0f) ? 1.0f : ((t1 < 0.0f) ? -1.0f : 0.0f);
    float g2 = (t2 > 0.0f) ? 1.0f : ((t2 < 0.0f) ? -1.0f : 0.0f);
    return be0 * g0 + be1 * g1 + be2 * g2;
}

// grid 512 = b(8) x h(32) x cout-half(2); 256 thr = 4 waves.
// wave w: couts ch*128 + w*32 .. +32, all 32 positions of row h.
__global__ __launch_bounds__(256, 2) void k_conv(
    const float* __restrict__ x, const float* __restrict__ shiftp,
    const float* __restrict__ beta, const void* __restrict__ wsv,
    float* __restrict__ out) {
    const unsigned short* wp = (const unsigned short*)((const char*)wsv + WS_WP_OFF);
    __shared__ __align__(16) unsigned short ldsx[3 * 34 * 128];   // 26112 B

    int bid = blockIdx.x;
    int ch  = bid & 1;
    int h   = (bid >> 1) & 31;
    int b   = bid >> 6;
    int tid = threadIdx.x;

    float s0 = shiftp[0], s1 = shiftp[1], s2 = shiftp[2];
    float be0 = beta[0], be1 = beta[1], be2 = beta[2];

    // stage X_eff (bf16) rows h-1..h+1, positions -1..32, XOR-swizzled
    for (int i = tid; i < 3 * 34 * 16; i += 256) {
        int cb   = i & 15;
        int pos  = (i >> 4) % 34;
        int drow = (i >> 4) / 34;
        int r  = h - 1 + drow;
        int wpos = pos - 1;
        unsigned short v[8] = {0, 0, 0, 0, 0, 0, 0, 0};
        if (r >= 0 && r < 32 && wpos >= 0 && wpos < 32) {
            const float* xp = &x[(((b * 32 + r) * 32) + wpos) * 128 + cb * 8];
            float4 x0 = *(const float4*)(xp);
            float4 x1 = *(const float4*)(xp + 4);
            float e[8] = {x0.x, x0.y, x0.z, x0.w, x1.x, x1.y, x1.z, x1.w};
            #pragma unroll
            for (int j = 0; j < 8; j++)
                v[j] = f2bf(xeff_one(e[j], s0, s1, s2, be0, be1, be2));
        }
        int row = drow * 34 + pos;
        int byteoff = row * 256 + ((cb * 16) ^ ((row & 7) << 4));
        *(short8*)((char*)ldsx + byteoff) = *(short8*)v;
    }
    __syncthreads();

    int lane = tid & 63;
    int wave = tid >> 6;
    int l15  = lane & 15;
    int kg   = lane >> 4;
    int coutbase = (ch << 7) + wave * 32;

    f32x4 acc[2][2];
    #pragma unroll
    for (int mt = 0; mt < 2; mt++)
        #pragma unroll
        for (int nt = 0; nt < 2; nt++) acc[mt][nt] = (f32x4){0.f, 0.f, 0.f, 0.f};

    #pragma unroll
    for (int dh = 0; dh < 3; dh++) {
        #pragma unroll
        for (int dw = 0; dw < 3; dw++) {
            int tap = dh * 3 + dw;
            int r0 = dh * 34 + l15 + dw;
            int r1 = r0 + 16;
            const unsigned short* wb =
                wp + ((tap * 256 + coutbase + l15) * 128 + kg * 8);
            #pragma unroll
            for (int c0 = 0; c0 < 128; c0 += 32) {
                int cbyte = c0 * 2 + kg * 16;
                short8 a0f8 = *(const short8*)((const char*)ldsx +
                               (r0 * 256 + (cbyte ^ ((r0 & 7) << 4))));
                short8 a1f8 = *(const short8*)((const char*)ldsx +
                               (r1 * 256 + (cbyte ^ ((r1 & 7) << 4))));
                short8 b0f8 = *(const short8*)(wb + c0);
                short8 b1f8 = *(const short8*)(wb + 16 * 128 + c0);
                acc[0][0] = __builtin_amdgcn_mfma_f32_16x16x32_bf16(a0f8, b0f8, acc[0][0], 0, 0, 0);
                acc[0][1] = __builtin_amdgcn_mfma_f32_16x16x32_bf16(a0f8, b1f8, acc[0][1], 0, 0, 0);
                acc[1][0] = __builtin_amdgcn_mfma_f32_16x16x32_bf16(a1f8, b0f8, acc[1][0], 0, 0, 0);
                acc[1][1] = __builtin_amdgcn_mfma_f32_16x16x32_bf16(a1f8, b1f8, acc[1][1], 0, 0, 0);
            }
        }
    }

    // D: col = lane&15 (cout), row = kg*4 + reg (pos within 16-tile)
    #pragma unroll
    for (int mt = 0; mt < 2; mt++) {
        #pragma unroll
        for (int nt = 0; nt < 2; nt++) {
            int col = coutbase + nt * 16 + l15;
            #pragma unroll
            for (int reg = 0; reg < 4; reg++) {
                int row = mt * 16 + kg * 4 + reg;
                out[(((b * 32 + h) * 32) + row) * 256 + col] = acc[mt][nt][reg];
            }
        }
    }
}

extern "C" void kernel_launch(void* const* d_in, const int* in_sizes, int n_in,
                              void* d_out, int out_size, void* d_ws, size_t ws_size,
                              hipStream_t stream) {
    const float* x      = (const float*)d_in[0];
    const float* w      = (const float*)d_in[1];
    const float* shiftp = (const float*)d_in[2];
    const float* beta   = (const float*)d_in[3];
    const float* a0     = (const float*)d_in[4];
    float* out = (float*)d_out;

    hipMemsetAsync(d_ws, 0, 160, stream);

    void* pre_args[] = {(void*)&w, (void*)&a0, (void*)&d_ws};
    hipLaunchCooperativeKernel((void*)k_pre, dim3(256), dim3(256),
                               pre_args, 0, stream);

    k_conv<<<512, 256, 0, stream>>>(x, shiftp, beta, d_ws, out);
}

// Round 6
// 75.296 us; speedup vs baseline: 2.1926x; 2.1926x over previous
//
#include <hip/hip_runtime.h>
#include <math.h>

#define KW_ELEMS 294912   // 3*3*128*256
#define LR_GD 0.01
#define NBLK_RED 64       // partial-reduction blocks

typedef __attribute__((ext_vector_type(8))) short short8;
typedef __attribute__((ext_vector_type(4))) float f32x4;

// ws layout (bytes):
//   0     : double stats_parts[64][2]      (sum, sumsq)        1024 B
//   1024  : int    gparts[64][15]                              3840 B
//   4864  : double cparts[64][5]                               2560 B
//   7424  : ushort W_packed[9][256][128]   (bf16, [tap][cout][cin])
#define WS_SP_OFF    0
#define WS_GP_OFF    1024
#define WS_CP_OFF    4864
#define WS_WP_OFF    7424

__device__ __forceinline__ unsigned short f2bf(float f) {
    union { float f; unsigned int u; } v; v.f = f;
    unsigned int r = v.u + 0x7fffu + ((v.u >> 16) & 1u);   // RNE
    return (unsigned short)(r >> 16);
}

// ---------------- K1: per-block partial sum / sumsq (f64) --------------------
__global__ __launch_bounds__(256) void k_stats(const float* __restrict__ w,
                                               void* __restrict__ wsv) {
    double* sp = (double*)((char*)wsv + WS_SP_OFF);
    __shared__ double s1[256];
    __shared__ double s2[256];
    int tid = threadIdx.x;
    double a = 0.0, b = 0.0;
    for (int i = blockIdx.x * 256 + tid; i < KW_ELEMS; i += NBLK_RED * 256) {
        double v = (double)w[i];
        a += v; b += v * v;
    }
    s1[tid] = a; s2[tid] = b;
    __syncthreads();
    for (int off = 128; off > 0; off >>= 1) {
        if (tid < off) { s1[tid] += s1[tid + off]; s2[tid] += s2[tid + off]; }
        __syncthreads();
    }
    if (tid == 0) { sp[blockIdx.x * 2] = s1[0]; sp[blockIdx.x * 2 + 1] = s2[0]; }
}

// ---------------- K2: per-block Gram partials (int) + c partials (f64) -------
__global__ __launch_bounds__(256) void k_gc(const float* __restrict__ w,
                                            void* __restrict__ wsv) {
    const double* sp = (const double*)((const char*)wsv + WS_SP_OFF);
    int*    gp = (int*)((char*)wsv + WS_GP_OFF);
    double* cp = (double*)((char*)wsv + WS_CP_OFF);

    __shared__ int    lg[4][15];
    __shared__ double lc[4][5];

    double sw = 0.0, sw2 = 0.0;
    for (int i = 0; i < NBLK_RED; i++) { sw += sp[i * 2]; sw2 += sp[i * 2 + 1]; }
    double mean = sw / (double)KW_ELEMS;
    double var  = sw2 / (double)KW_ELEMS - mean * mean;
    float meanf = (float)mean;
    float sigf  = sqrtf((float)var);

    float sh[5];
    #pragma unroll
    for (int m = 0; m < 5; m++) sh[m] = (-1.0f + 0.5f * (float)m) * sigf;

    int g[15]; double c[5];
    #pragma unroll
    for (int t = 0; t < 15; t++) g[t] = 0;
    #pragma unroll
    for (int i = 0; i < 5; i++) c[i] = 0.0;

    for (int idx = blockIdx.x * 256 + threadIdx.x; idx < KW_ELEMS;
         idx += NBLK_RED * 256) {
        float wf = w[idx];
        float base = wf - meanf;
        int s[5];
        #pragma unroll
        for (int m = 0; m < 5; m++) {
            float arg = base + sh[m];
            s[m] = (arg > 0.0f) ? 1 : ((arg < 0.0f) ? -1 : 0);
        }
        int t = 0;
        #pragma unroll
        for (int i = 0; i < 5; i++) {
            #pragma unroll
            for (int j = i; j < 5; j++) { g[t] += s[i] * s[j]; t++; }
            c[i] += (double)s[i] * (double)wf;
        }
    }
    #pragma unroll
    for (int t = 0; t < 15; t++) {
        int v = g[t];
        for (int off = 32; off > 0; off >>= 1) v += __shfl_down(v, off, 64);
        g[t] = v;
    }
    #pragma unroll
    for (int i = 0; i < 5; i++) {
        double v = c[i];
        for (int off = 32; off > 0; off >>= 1) v += __shfl_down(v, off, 64);
        c[i] = v;
    }
    int wave = threadIdx.x >> 6;
    if ((threadIdx.x & 63) == 0) {
        #pragma unroll
        for (int t = 0; t < 15; t++) lg[wave][t] = g[t];
        #pragma unroll
        for (int i = 0; i < 5; i++) lc[wave][i] = c[i];
    }
    __syncthreads();
    if (threadIdx.x == 0) {
        #pragma unroll
        for (int t = 0; t < 15; t++)
            gp[blockIdx.x * 15 + t] = lg[0][t] + lg[1][t] + lg[2][t] + lg[3][t];
        #pragma unroll
        for (int i = 0; i < 5; i++)
            cp[blockIdx.x * 5 + i] = lc[0][i] + lc[1][i] + lc[2][i] + lc[3][i];
    }
}

// ---------------- closed-form 500-step GD (1 thread, f64) --------------------
__device__ __forceinline__ void mm5(double* __restrict__ D,
                                    const double* __restrict__ X,
                                    const double* __restrict__ Y) {
    #pragma unroll
    for (int i = 0; i < 5; i++) {
        #pragma unroll
        for (int j = 0; j < 5; j++) {
            double s = 0.0;
            #pragma unroll
            for (int k = 0; k < 5; k++) s += X[i * 5 + k] * Y[k * 5 + j];
            D[i * 5 + j] = s;
        }
    }
}

__device__ void compute_alphas_from_parts(const int* gp, const double* cp,
                                          const float* a0f, float* alph_out) {
    int gi[15]; double ci5[5];
    #pragma unroll
    for (int t = 0; t < 15; t++) gi[t] = 0;
    #pragma unroll
    for (int i = 0; i < 5; i++) ci5[i] = 0.0;
    for (int b = 0; b < NBLK_RED; b++) {
        #pragma unroll
        for (int t = 0; t < 15; t++) gi[t] += gp[b * 15 + t];
        #pragma unroll
        for (int i = 0; i < 5; i++) ci5[i] += cp[b * 5 + i];
    }

    double G[25], C[5];
    {
        int t = 0;
        #pragma unroll
        for (int i = 0; i < 5; i++) {
            #pragma unroll
            for (int j = i; j < 5; j++) {
                double v = (double)gi[t] / (double)KW_ELEMS; t++;
                G[i * 5 + j] = v; G[j * 5 + i] = v;
            }
        }
    }
    #pragma unroll
    for (int i = 0; i < 5; i++) C[i] = ci5[i] / (double)KW_ELEMS;

    double L[25];
    #pragma unroll
    for (int i = 0; i < 25; i++) L[i] = 0.0;
    #pragma unroll
    for (int i = 0; i < 5; i++) {
        #pragma unroll
        for (int j = 0; j <= i; j++) {
            double s = G[i * 5 + j];
            #pragma unroll
            for (int k = 0; k < j; k++) s -= L[i * 5 + k] * L[j * 5 + k];
            if (i == j) L[i * 5 + j] = sqrt(s);
            else        L[i * 5 + j] = s / L[j * 5 + j];
        }
    }
    double y[5], astar[5];
    #pragma unroll
    for (int i = 0; i < 5; i++) {
        double s = C[i];
        #pragma unroll
        for (int k = 0; k < i; k++) s -= L[i * 5 + k] * y[k];
        y[i] = s / L[i * 5 + i];
    }
    #pragma unroll
    for (int ii = 0; ii < 5; ii++) {
        int i = 4 - ii;
        double s = y[i];
        #pragma unroll
        for (int k = 0; k < 5; k++) if (k > i) s -= L[k * 5 + i] * astar[k];
        astar[i] = s / L[i * 5 + i];
    }
    double A[25], R[25], T[25];
    #pragma unroll
    for (int i = 0; i < 25; i++) A[i] = ((i % 6) == 0 ? 1.0 : 0.0) - LR_GD * G[i];
    #pragma unroll
    for (int i = 0; i < 25; i++) R[i] = A[i];
    const int bits[8] = {1, 1, 1, 1, 0, 1, 0, 0};   // 500, square-and-multiply
    for (int s = 0; s < 8; s++) {
        mm5(T, R, R);
        if (bits[s]) { mm5(R, T, A); }
        else {
            #pragma unroll
            for (int i = 0; i < 25; i++) R[i] = T[i];
        }
    }
    double d0[5];
    #pragma unroll
    for (int i = 0; i < 5; i++) d0[i] = (double)a0f[i] - astar[i];
    #pragma unroll
    for (int i = 0; i < 5; i++) {
        double s = astar[i];
        #pragma unroll
        for (int j = 0; j < 5; j++) s += R[i * 5 + j] * d0[j];
        alph_out[i] = (float)s;
    }
}

// ---------------- K3: W_packed[tap][cout][cin] bf16 --------------------------
// grid 144 = tap(9) x cin-quarter(4) x cout-quarter(4).
// Loads fly while thread 0 reduces partials + solves alphas.
__global__ __launch_bounds__(256) void k_weff(const float* __restrict__ w,
                                              const float* __restrict__ a0f,
                                              void* __restrict__ wsv) {
    const double* sp = (const double*)((const char*)wsv + WS_SP_OFF);
    const int*    gp = (const int*)((const char*)wsv + WS_GP_OFF);
    const double* cp = (const double*)((const char*)wsv + WS_CP_OFF);
    unsigned short* wpk = (unsigned short*)((char*)wsv + WS_WP_OFF);

    __shared__ float alph[5];
    __shared__ float tile[32][64];

    int tid   = threadIdx.x;
    int tap   = blockIdx.x >> 4;
    int rest  = blockIdx.x & 15;
    int cin0  = (rest >> 2) * 32;
    int cout0 = (rest & 3) * 64;

    // phase A: issue tile loads (2 float4 per thread) — in flight during solve
    int i0 = tid, i1 = tid + 256;
    int ci0 = i0 >> 4, f40 = i0 & 15;
    int ci1 = i1 >> 4, f41 = i1 & 15;
    float4 v0 = *(const float4*)(&w[(tap * 128 + cin0 + ci0) * 256 + cout0 + f40 * 4]);
    float4 v1 = *(const float4*)(&w[(tap * 128 + cin0 + ci1) * 256 + cout0 + f41 * 4]);

    // stats (every thread, cheap: 128 cached loads)
    double sw = 0.0, sw2 = 0.0;
    for (int i = 0; i < NBLK_RED; i++) { sw += sp[i * 2]; sw2 += sp[i * 2 + 1]; }
    double mean = sw / (double)KW_ELEMS;
    double var  = sw2 / (double)KW_ELEMS - mean * mean;
    float meanf = (float)mean;
    float sigf  = sqrtf((float)var);

    // phase B: serial solve on thread 0
    if (tid == 0) compute_alphas_from_parts(gp, cp, a0f, alph);
    __syncthreads();

    float a0 = alph[0], a1 = alph[1], a2 = alph[2], a3 = alph[3], a4 = alph[4];
    float al[5] = {a0, a1, a2, a3, a4};

    // phase C: combine + LDS transpose + bf16 pack
    {
        float r[4] = {v0.x, v0.y, v0.z, v0.w};
        #pragma unroll
        for (int j = 0; j < 4; j++) {
            float base = r[j] - meanf;
            float acc = 0.0f;
            #pragma unroll
            for (int m = 0; m < 5; m++) {
                float arg = base + (-1.0f + 0.5f * (float)m) * sigf;
                float s = (arg > 0.0f) ? 1.0f : ((arg < 0.0f) ? -1.0f : 0.0f);
                acc += al[m] * s;
            }
            tile[ci0][f40 * 4 + j] = acc;
        }
        float r1[4] = {v1.x, v1.y, v1.z, v1.w};
        #pragma unroll
        for (int j = 0; j < 4; j++) {
            float base = r1[j] - meanf;
            float acc = 0.0f;
            #pragma unroll
            for (int m = 0; m < 5; m++) {
                float arg = base + (-1.0f + 0.5f * (float)m) * sigf;
                float s = (arg > 0.0f) ? 1.0f : ((arg < 0.0f) ? -1.0f : 0.0f);
                acc += al[m] * s;
            }
            tile[ci1][f41 * 4 + j] = acc;
        }
    }
    __syncthreads();

    int cc  = tid & 63;
    int ch8 = tid >> 6;          // 0..3: 8-cin chunk
    unsigned short ob[8];
    #pragma unroll
    for (int k = 0; k < 8; k++) ob[k] = f2bf(tile[ch8 * 8 + k][cc]);
    unsigned short* dst = wpk + (tap * 256 + cout0 + cc) * 128 + cin0 + ch8 * 8;
    *(short8*)dst = *(short8*)ob;
}

// ---------------- K4: fused binarize-x + 3x3 conv via bf16 MFMA --------------
__device__ __forceinline__ float xeff_one(float xv, float s0, float s1, float s2,
                                          float be0, float be1, float be2) {
    float t0 = fminf(fmaxf(xv + s0, 0.0f), 1.0f) - 0.5f;
    float t1 = fminf(fmaxf(xv + s1, 0.0f), 1.0f) - 0.5f;
    float t2 = fminf(fmaxf(xv + s2, 0.0f), 1.0f) - 0.5f;
    float g0 = (t0 > 0.0f) ? 1.0f : ((t0 < 0.0f) ? -1.0f : 0.0f);
    float g1 = (t1 > 0.0f) ? 1.0f : ((t1 < 0.0f) ? -1.0f : 0.0f);
    float g2 = (t2 > 0.0f) ? 1.0f : ((t2 < 0.0f) ? -1.0f : 0.0f);
    return be0 * g0 + be1 * g1 + be2 * g2;
}

// grid 512 = b(8) x h(32) x cout-half(2); 256 thr = 4 waves.
__global__ __launch_bounds__(256, 2) void k_conv(
    const float* __restrict__ x, const float* __restrict__ shiftp,
    const float* __restrict__ beta, const void* __restrict__ wsv,
    float* __restrict__ out) {
    const unsigned short* wp = (const unsigned short*)((const char*)wsv + WS_WP_OFF);
    __shared__ __align__(16) unsigned short ldsx[3 * 34 * 128];   // 26112 B

    int bid = blockIdx.x;
    int ch  = bid & 1;
    int h   = (bid >> 1) & 31;
    int b   = bid >> 6;
    int tid = threadIdx.x;

    float s0 = shiftp[0], s1 = shiftp[1], s2 = shiftp[2];
    float be0 = beta[0], be1 = beta[1], be2 = beta[2];

    // stage X_eff (bf16) rows h-1..h+1, positions -1..32, XOR-swizzled
    for (int i = tid; i < 3 * 34 * 16; i += 256) {
        int cb   = i & 15;
        int pos  = (i >> 4) % 34;
        int drow = (i >> 4) / 34;
        int r  = h - 1 + drow;
        int wpos = pos - 1;
        unsigned short v[8] = {0, 0, 0, 0, 0, 0, 0, 0};
        if (r >= 0 && r < 32 && wpos >= 0 && wpos < 32) {
            const float* xp = &x[(((b * 32 + r) * 32) + wpos) * 128 + cb * 8];
            float4 x0 = *(const float4*)(xp);
            float4 x1 = *(const float4*)(xp + 4);
            float e[8] = {x0.x, x0.y, x0.z, x0.w, x1.x, x1.y, x1.z, x1.w};
            #pragma unroll
            for (int j = 0; j < 8; j++)
                v[j] = f2bf(xeff_one(e[j], s0, s1, s2, be0, be1, be2));
        }
        int row = drow * 34 + pos;
        int byteoff = row * 256 + ((cb * 16) ^ ((row & 7) << 4));
        *(short8*)((char*)ldsx + byteoff) = *(short8*)v;
    }
    __syncthreads();

    int lane = tid & 63;
    int wave = tid >> 6;
    int l15  = lane & 15;
    int kg   = lane >> 4;
    int coutbase = (ch << 7) + wave * 32;

    f32x4 acc[2][2];
    #pragma unroll
    for (int mt = 0; mt < 2; mt++)
        #pragma unroll
        for (int nt = 0; nt < 2; nt++) acc[mt][nt] = (f32x4){0.f, 0.f, 0.f, 0.f};

    #pragma unroll
    for (int dh = 0; dh < 3; dh++) {
        #pragma unroll
        for (int dw = 0; dw < 3; dw++) {
            int tap = dh * 3 + dw;
            int r0 = dh * 34 + l15 + dw;
            int r1 = r0 + 16;
            const unsigned short* wb =
                wp + ((tap * 256 + coutbase + l15) * 128 + kg * 8);
            #pragma unroll
            for (int c0 = 0; c0 < 128; c0 += 32) {
                int cbyte = c0 * 2 + kg * 16;
                short8 a0f8 = *(const short8*)((const char*)ldsx +
                               (r0 * 256 + (cbyte ^ ((r0 & 7) << 4))));
                short8 a1f8 = *(const short8*)((const char*)ldsx +
                               (r1 * 256 + (cbyte ^ ((r1 & 7) << 4))));
                short8 b0f8 = *(const short8*)(wb + c0);
                short8 b1f8 = *(const short8*)(wb + 16 * 128 + c0);
                acc[0][0] = __builtin_amdgcn_mfma_f32_16x16x32_bf16(a0f8, b0f8, acc[0][0], 0, 0, 0);
                acc[0][1] = __builtin_amdgcn_mfma_f32_16x16x32_bf16(a0f8, b1f8, acc[0][1], 0, 0, 0);
                acc[1][0] = __builtin_amdgcn_mfma_f32_16x16x32_bf16(a1f8, b0f8, acc[1][0], 0, 0, 0);
                acc[1][1] = __builtin_amdgcn_mfma_f32_16x16x32_bf16(a1f8, b1f8, acc[1][1], 0, 0, 0);
            }
        }
    }

    // D: col = lane&15 (cout), row = kg*4 + reg (pos within 16-tile)
    #pragma unroll
    for (int mt = 0; mt < 2; mt++) {
        #pragma unroll
        for (int nt = 0; nt < 2; nt++) {
            int col = coutbase + nt * 16 + l15;
            #pragma unroll
            for (int reg = 0; reg < 4; reg++) {
                int row = mt * 16 + kg * 4 + reg;
                out[(((b * 32 + h) * 32) + row) * 256 + col] = acc[mt][nt][reg];
            }
        }
    }
}

extern "C" void kernel_launch(void* const* d_in, const int* in_sizes, int n_in,
                              void* d_out, int out_size, void* d_ws, size_t ws_size,
                              hipStream_t stream) {
    const float* x      = (const float*)d_in[0];
    const float* w      = (const float*)d_in[1];
    const float* shiftp = (const float*)d_in[2];
    const float* beta   = (const float*)d_in[3];
    const float* a0     = (const float*)d_in[4];
    float* out = (float*)d_out;

    k_stats<<<NBLK_RED, 256, 0, stream>>>(w, d_ws);
    k_gc<<<NBLK_RED, 256, 0, stream>>>(w, d_ws);
    k_weff<<<144, 256, 0, stream>>>(w, a0, d_ws);
    k_conv<<<512, 256, 0, stream>>>(x, shiftp, beta, d_ws, out);
}

// Round 7
// 65.314 us; speedup vs baseline: 2.5277x; 1.1528x over previous
//
#include <hip/hip_runtime.h>
#include <math.h>

#define KW_ELEMS 294912   // 3*3*128*256
#define LR_GD 0.01
#define NBLK_RED 64       // partial-reduction blocks

typedef __attribute__((ext_vector_type(8))) short short8;
typedef __attribute__((ext_vector_type(4))) float f32x4;

// ws layout (bytes):
//   0     : double stats_parts[64][2]      (sum, sumsq)   1024 B
//   1024  : int    Gint[15]   (atomic finals)               60 B
//   1088  : double c5[5]      (atomic finals)               40 B
//   1152  : ushort W_packed[9][256][128]   (bf16, [tap][cout][cin])
#define WS_SP_OFF    0
#define WS_G_OFF     1024
#define WS_C_OFF     1088
#define WS_WP_OFF    1152

__device__ __forceinline__ unsigned short f2bf(float f) {
    union { float f; unsigned int u; } v; v.f = f;
    unsigned int r = v.u + 0x7fffu + ((v.u >> 16) & 1u);   // RNE
    return (unsigned short)(r >> 16);
}

// lane-parallel read of the 128 stats partials + butterfly reduce.
// returns (sum, sumsq) in ALL lanes of the wave.
__device__ __forceinline__ void read_stats(const double* sp, double& sw, double& sw2) {
    int lane = threadIdx.x & 63;
    double a = sp[2 * lane];
    double b = sp[2 * lane + 1];
    #pragma unroll
    for (int off = 32; off > 0; off >>= 1) {
        a += __shfl_xor(a, off, 64);
        b += __shfl_xor(b, off, 64);
    }
    sw = a; sw2 = b;
}

// ---------------- K1: per-block partial sum / sumsq (f64) + zero atomics -----
__global__ __launch_bounds__(256) void k_stats(const float* __restrict__ w,
                                               void* __restrict__ wsv) {
    double* sp = (double*)((char*)wsv + WS_SP_OFF);
    int*    gw = (int*)((char*)wsv + WS_G_OFF);
    double* cw = (double*)((char*)wsv + WS_C_OFF);
    __shared__ double s1[256];
    __shared__ double s2[256];
    int tid = threadIdx.x;

    // zero the atomic accumulators (visible to k_gc via kernel boundary)
    if (blockIdx.x == 0) {
        if (tid < 15) gw[tid] = 0;
        if (tid >= 32 && tid < 37) cw[tid - 32] = 0.0;
    }

    double a = 0.0, b = 0.0;
    for (int i = blockIdx.x * 256 + tid; i < KW_ELEMS; i += NBLK_RED * 256) {
        double v = (double)w[i];
        a += v; b += v * v;
    }
    s1[tid] = a; s2[tid] = b;
    __syncthreads();
    for (int off = 128; off > 0; off >>= 1) {
        if (tid < off) { s1[tid] += s1[tid + off]; s2[tid] += s2[tid + off]; }
        __syncthreads();
    }
    if (tid == 0) { sp[blockIdx.x * 2] = s1[0]; sp[blockIdx.x * 2 + 1] = s2[0]; }
}

// ---------------- K2: Gram counts + c, atomic finals -------------------------
__global__ __launch_bounds__(256) void k_gc(const float* __restrict__ w,
                                            void* __restrict__ wsv) {
    const double* sp = (const double*)((const char*)wsv + WS_SP_OFF);
    int*    gw = (int*)((char*)wsv + WS_G_OFF);
    double* cw = (double*)((char*)wsv + WS_C_OFF);

    __shared__ int    lg[4][15];
    __shared__ double lc[4][5];

    double sw, sw2;
    read_stats(sp, sw, sw2);
    double mean = sw / (double)KW_ELEMS;
    double var  = sw2 / (double)KW_ELEMS - mean * mean;
    float meanf = (float)mean;
    float sigf  = sqrtf((float)var);

    float sh[5];
    #pragma unroll
    for (int m = 0; m < 5; m++) sh[m] = (-1.0f + 0.5f * (float)m) * sigf;

    int g[15]; double c[5];
    #pragma unroll
    for (int t = 0; t < 15; t++) g[t] = 0;
    #pragma unroll
    for (int i = 0; i < 5; i++) c[i] = 0.0;

    for (int idx = blockIdx.x * 256 + threadIdx.x; idx < KW_ELEMS;
         idx += NBLK_RED * 256) {
        float wf = w[idx];
        float base = wf - meanf;
        int s[5];
        #pragma unroll
        for (int m = 0; m < 5; m++) {
            float arg = base + sh[m];
            s[m] = (arg > 0.0f) ? 1 : ((arg < 0.0f) ? -1 : 0);
        }
        int t = 0;
        #pragma unroll
        for (int i = 0; i < 5; i++) {
            #pragma unroll
            for (int j = i; j < 5; j++) { g[t] += s[i] * s[j]; t++; }
            c[i] += (double)s[i] * (double)wf;
        }
    }
    #pragma unroll
    for (int t = 0; t < 15; t++) {
        int v = g[t];
        for (int off = 32; off > 0; off >>= 1) v += __shfl_down(v, off, 64);
        g[t] = v;
    }
    #pragma unroll
    for (int i = 0; i < 5; i++) {
        double v = c[i];
        for (int off = 32; off > 0; off >>= 1) v += __shfl_down(v, off, 64);
        c[i] = v;
    }
    int wave = threadIdx.x >> 6;
    if ((threadIdx.x & 63) == 0) {
        #pragma unroll
        for (int t = 0; t < 15; t++) lg[wave][t] = g[t];
        #pragma unroll
        for (int i = 0; i < 5; i++) lc[wave][i] = c[i];
    }
    __syncthreads();
    if (threadIdx.x == 0) {
        #pragma unroll
        for (int t = 0; t < 15; t++)
            atomicAdd(&gw[t], lg[0][t] + lg[1][t] + lg[2][t] + lg[3][t]);
        #pragma unroll
        for (int i = 0; i < 5; i++)
            atomicAdd(&cw[i], lc[0][i] + lc[1][i] + lc[2][i] + lc[3][i]);
    }
}

// ---------------- closed-form 500-step GD (1 thread, f64) --------------------
__device__ __forceinline__ void mm5(double* __restrict__ D,
                                    const double* __restrict__ X,
                                    const double* __restrict__ Y) {
    #pragma unroll
    for (int i = 0; i < 5; i++) {
        #pragma unroll
        for (int j = 0; j < 5; j++) {
            double s = 0.0;
            #pragma unroll
            for (int k = 0; k < 5; k++) s += X[i * 5 + k] * Y[k * 5 + j];
            D[i * 5 + j] = s;
        }
    }
}

__device__ void compute_alphas(const int* gw, const double* cw,
                               const float* a0f, float* alph_out) {
    double G[25], C[5];
    {
        int t = 0;
        #pragma unroll
        for (int i = 0; i < 5; i++) {
            #pragma unroll
            for (int j = i; j < 5; j++) {
                double v = (double)gw[t] / (double)KW_ELEMS; t++;
                G[i * 5 + j] = v; G[j * 5 + i] = v;
            }
        }
    }
    #pragma unroll
    for (int i = 0; i < 5; i++) C[i] = cw[i] / (double)KW_ELEMS;

    double L[25];
    #pragma unroll
    for (int i = 0; i < 25; i++) L[i] = 0.0;
    #pragma unroll
    for (int i = 0; i < 5; i++) {
        #pragma unroll
        for (int j = 0; j <= i; j++) {
            double s = G[i * 5 + j];
            #pragma unroll
            for (int k = 0; k < j; k++) s -= L[i * 5 + k] * L[j * 5 + k];
            if (i == j) L[i * 5 + j] = sqrt(s);
            else        L[i * 5 + j] = s / L[j * 5 + j];
        }
    }
    double y[5], astar[5];
    #pragma unroll
    for (int i = 0; i < 5; i++) {
        double s = C[i];
        #pragma unroll
        for (int k = 0; k < i; k++) s -= L[i * 5 + k] * y[k];
        y[i] = s / L[i * 5 + i];
    }
    #pragma unroll
    for (int ii = 0; ii < 5; ii++) {
        int i = 4 - ii;
        double s = y[i];
        #pragma unroll
        for (int k = 0; k < 5; k++) if (k > i) s -= L[k * 5 + i] * astar[k];
        astar[i] = s / L[i * 5 + i];
    }
    double A[25], R[25], T[25];
    #pragma unroll
    for (int i = 0; i < 25; i++) A[i] = ((i % 6) == 0 ? 1.0 : 0.0) - LR_GD * G[i];
    #pragma unroll
    for (int i = 0; i < 25; i++) R[i] = A[i];
    const int bits[8] = {1, 1, 1, 1, 0, 1, 0, 0};   // 500, square-and-multiply
    for (int s = 0; s < 8; s++) {
        mm5(T, R, R);
        if (bits[s]) { mm5(R, T, A); }
        else {
            #pragma unroll
            for (int i = 0; i < 25; i++) R[i] = T[i];
        }
    }
    double d0[5];
    #pragma unroll
    for (int i = 0; i < 5; i++) d0[i] = (double)a0f[i] - astar[i];
    #pragma unroll
    for (int i = 0; i < 5; i++) {
        double s = astar[i];
        #pragma unroll
        for (int j = 0; j < 5; j++) s += R[i * 5 + j] * d0[j];
        alph_out[i] = (float)s;
    }
}

// ---------------- K3: W_packed[tap][cout][cin] bf16 --------------------------
// grid 144 = tap(9) x cin-quarter(4) x cout-quarter(4).
__global__ __launch_bounds__(256) void k_weff(const float* __restrict__ w,
                                              const float* __restrict__ a0f,
                                              void* __restrict__ wsv) {
    const double* sp = (const double*)((const char*)wsv + WS_SP_OFF);
    const int*    gw = (const int*)((const char*)wsv + WS_G_OFF);
    const double* cw = (const double*)((const char*)wsv + WS_C_OFF);
    unsigned short* wpk = (unsigned short*)((char*)wsv + WS_WP_OFF);

    __shared__ float alph[5];
    __shared__ float tile[32][64];

    int tid   = threadIdx.x;
    int tap   = blockIdx.x >> 4;
    int rest  = blockIdx.x & 15;
    int cin0  = (rest >> 2) * 32;
    int cout0 = (rest & 3) * 64;

    // phase A: issue tile loads — in flight during solve
    int i0 = tid, i1 = tid + 256;
    int ci0 = i0 >> 4, f40 = i0 & 15;
    int ci1 = i1 >> 4, f41 = i1 & 15;
    float4 v0 = *(const float4*)(&w[(tap * 128 + cin0 + ci0) * 256 + cout0 + f40 * 4]);
    float4 v1 = *(const float4*)(&w[(tap * 128 + cin0 + ci1) * 256 + cout0 + f41 * 4]);

    double sw, sw2;
    read_stats(sp, sw, sw2);
    double mean = sw / (double)KW_ELEMS;
    double var  = sw2 / (double)KW_ELEMS - mean * mean;
    float meanf = (float)mean;
    float sigf  = sqrtf((float)var);

    // phase B: serial solve on thread 0 (input = one 20-load burst)
    if (tid == 0) compute_alphas(gw, cw, a0f, alph);
    __syncthreads();

    float al[5] = {alph[0], alph[1], alph[2], alph[3], alph[4]};

    // phase C: combine + LDS transpose + bf16 pack
    {
        float r[4] = {v0.x, v0.y, v0.z, v0.w};
        #pragma unroll
        for (int j = 0; j < 4; j++) {
            float base = r[j] - meanf;
            float acc = 0.0f;
            #pragma unroll
            for (int m = 0; m < 5; m++) {
                float arg = base + (-1.0f + 0.5f * (float)m) * sigf;
                float s = (arg > 0.0f) ? 1.0f : ((arg < 0.0f) ? -1.0f : 0.0f);
                acc += al[m] * s;
            }
            tile[ci0][f40 * 4 + j] = acc;
        }
        float r1[4] = {v1.x, v1.y, v1.z, v1.w};
        #pragma unroll
        for (int j = 0; j < 4; j++) {
            float base = r1[j] - meanf;
            float acc = 0.0f;
            #pragma unroll
            for (int m = 0; m < 5; m++) {
                float arg = base + (-1.0f + 0.5f * (float)m) * sigf;
                float s = (arg > 0.0f) ? 1.0f : ((arg < 0.0f) ? -1.0f : 0.0f);
                acc += al[m] * s;
            }
            tile[ci1][f41 * 4 + j] = acc;
        }
    }
    __syncthreads();

    int cc  = tid & 63;
    int ch8 = tid >> 6;          // 0..3: 8-cin chunk
    unsigned short ob[8];
    #pragma unroll
    for (int k = 0; k < 8; k++) ob[k] = f2bf(tile[ch8 * 8 + k][cc]);
    unsigned short* dst = wpk + (tap * 256 + cout0 + cc) * 128 + cin0 + ch8 * 8;
    *(short8*)dst = *(short8*)ob;
}

// ---------------- K4: fused binarize-x + 3x3 conv via bf16 MFMA --------------
__device__ __forceinline__ float xeff_one(float xv, float s0, float s1, float s2,
                                          float be0, float be1, float be2) {
    float t0 = fminf(fmaxf(xv + s0, 0.0f), 1.0f) - 0.5f;
    float t1 = fminf(fmaxf(xv + s1, 0.0f), 1.0f) - 0.5f;
    float t2 = fminf(fmaxf(xv + s2, 0.0f), 1.0f) - 0.5f;
    float g0 = (t0 > 0.0f) ? 1.0f : ((t0 < 0.0f) ? -1.0f : 0.0f);
    float g1 = (t1 > 0.0f) ? 1.0f : ((t1 < 0.0f) ? -1.0f : 0.0f);
    float g2 = (t2 > 0.0f) ? 1.0f : ((t2 < 0.0f) ? -1.0f : 0.0f);
    return be0 * g0 + be1 * g1 + be2 * g2;
}

// grid 512 = b(8) x h(32) x cout-half(2); 256 thr = 4 waves.
__global__ __launch_bounds__(256, 2) void k_conv(
    const float* __restrict__ x, const float* __restrict__ shiftp,
    const float* __restrict__ beta, const void* __restrict__ wsv,
    float* __restrict__ out) {
    const unsigned short* wp = (const unsigned short*)((const char*)wsv + WS_WP_OFF);
    __shared__ __align__(16) unsigned short ldsx[3 * 34 * 128];   // 26112 B

    int bid = blockIdx.x;
    int ch  = bid & 1;
    int h   = (bid >> 1) & 31;
    int b   = bid >> 6;
    int tid = threadIdx.x;

    float s0 = shiftp[0], s1 = shiftp[1], s2 = shiftp[2];
    float be0 = beta[0], be1 = beta[1], be2 = beta[2];

    // stage X_eff (bf16) rows h-1..h+1, positions -1..32, XOR-swizzled
    for (int i = tid; i < 3 * 34 * 16; i += 256) {
        int cb   = i & 15;
        int pos  = (i >> 4) % 34;
        int drow = (i >> 4) / 34;
        int r  = h - 1 + drow;
        int wpos = pos - 1;
        unsigned short v[8] = {0, 0, 0, 0, 0, 0, 0, 0};
        if (r >= 0 && r < 32 && wpos >= 0 && wpos < 32) {
            const float* xp = &x[(((b * 32 + r) * 32) + wpos) * 128 + cb * 8];
            float4 x0 = *(const float4*)(xp);
            float4 x1 = *(const float4*)(xp + 4);
            float e[8] = {x0.x, x0.y, x0.z, x0.w, x1.x, x1.y, x1.z, x1.w};
            #pragma unroll
            for (int j = 0; j < 8; j++)
                v[j] = f2bf(xeff_one(e[j], s0, s1, s2, be0, be1, be2));
        }
        int row = drow * 34 + pos;
        int byteoff = row * 256 + ((cb * 16) ^ ((row & 7) << 4));
        *(short8*)((char*)ldsx + byteoff) = *(short8*)v;
    }
    __syncthreads();

    int lane = tid & 63;
    int wave = tid >> 6;
    int l15  = lane & 15;
    int kg   = lane >> 4;
    int coutbase = (ch << 7) + wave * 32;

    f32x4 acc[2][2];
    #pragma unroll
    for (int mt = 0; mt < 2; mt++)
        #pragma unroll
        for (int nt = 0; nt < 2; nt++) acc[mt][nt] = (f32x4){0.f, 0.f, 0.f, 0.f};

    #pragma unroll
    for (int dh = 0; dh < 3; dh++) {
        #pragma unroll
        for (int dw = 0; dw < 3; dw++) {
            int tap = dh * 3 + dw;
            int r0 = dh * 34 + l15 + dw;
            int r1 = r0 + 16;
            const unsigned short* wb =
                wp + ((tap * 256 + coutbase + l15) * 128 + kg * 8);
            #pragma unroll
            for (int c0 = 0; c0 < 128; c0 += 32) {
                int cbyte = c0 * 2 + kg * 16;
                short8 a0f8 = *(const short8*)((const char*)ldsx +
                               (r0 * 256 + (cbyte ^ ((r0 & 7) << 4))));
                short8 a1f8 = *(const short8*)((const char*)ldsx +
                               (r1 * 256 + (cbyte ^ ((r1 & 7) << 4))));
                short8 b0f8 = *(const short8*)(wb + c0);
                short8 b1f8 = *(const short8*)(wb + 16 * 128 + c0);
                acc[0][0] = __builtin_amdgcn_mfma_f32_16x16x32_bf16(a0f8, b0f8, acc[0][0], 0, 0, 0);
                acc[0][1] = __builtin_amdgcn_mfma_f32_16x16x32_bf16(a0f8, b1f8, acc[0][1], 0, 0, 0);
                acc[1][0] = __builtin_amdgcn_mfma_f32_16x16x32_bf16(a1f8, b0f8, acc[1][0], 0, 0, 0);
                acc[1][1] = __builtin_amdgcn_mfma_f32_16x16x32_bf16(a1f8, b1f8, acc[1][1], 0, 0, 0);
            }
        }
    }

    // D: col = lane&15 (cout), row = kg*4 + reg (pos within 16-tile)
    #pragma unroll
    for (int mt = 0; mt < 2; mt++) {
        #pragma unroll
        for (int nt = 0; nt < 2; nt++) {
            int col = coutbase + nt * 16 + l15;
            #pragma unroll
            for (int reg = 0; reg < 4; reg++) {
                int row = mt * 16 + kg * 4 + reg;
                out[(((b * 32 + h) * 32) + row) * 256 + col] = acc[mt][nt][reg];
            }
        }
    }
}

extern "C" void kernel_launch(void* const* d_in, const int* in_sizes, int n_in,
                              void* d_out, int out_size, void* d_ws, size_t ws_size,
                              hipStream_t stream) {
    const float* x      = (const float*)d_in[0];
    const float* w      = (const float*)d_in[1];
    const float* shiftp = (const float*)d_in[2];
    const float* beta   = (const float*)d_in[3];
    const float* a0     = (const float*)d_in[4];
    float* out = (float*)d_out;

    k_stats<<<NBLK_RED, 256, 0, stream>>>(w, d_ws);
    k_gc<<<NBLK_RED, 256, 0, stream>>>(w, d_ws);
    k_weff<<<144, 256, 0, stream>>>(w, a0, d_ws);
    k_conv<<<512, 256, 0, stream>>>(x, shiftp, beta, d_ws, out);
}

// Round 8
// 58.334 us; speedup vs baseline: 2.8302x; 1.1197x over previous
//
#include <hip/hip_runtime.h>
#include <math.h>

#define KW_ELEMS 294912   // 3*3*128*256
#define LR_GD 0.01
#define NBLK_RED 64       // partial-reduction blocks

typedef __attribute__((ext_vector_type(8))) short short8;
typedef __attribute__((ext_vector_type(4))) float f32x4;

// ws layout (bytes):
//   0     : double stats_parts[64][2]      (sum, sumsq)   1024 B
//   1024  : int    Gint[15]   (atomic finals)               60 B
//   1088  : double c5[5]      (atomic finals)               40 B
//   1152  : ushort W2[9][4][4][256][8]   (bf16, [tap][cin32][kg][cout][cin8])
#define WS_SP_OFF    0
#define WS_G_OFF     1024
#define WS_C_OFF     1088
#define WS_WP_OFF    1152

__device__ __forceinline__ unsigned short f2bf(float f) {
    union { float f; unsigned int u; } v; v.f = f;
    unsigned int r = v.u + 0x7fffu + ((v.u >> 16) & 1u);   // RNE
    return (unsigned short)(r >> 16);
}

// lane-parallel read of the 128 stats partials + butterfly reduce.
__device__ __forceinline__ void read_stats(const double* sp, double& sw, double& sw2) {
    int lane = threadIdx.x & 63;
    double a = sp[2 * lane];
    double b = sp[2 * lane + 1];
    #pragma unroll
    for (int off = 32; off > 0; off >>= 1) {
        a += __shfl_xor(a, off, 64);
        b += __shfl_xor(b, off, 64);
    }
    sw = a; sw2 = b;
}

// ---------------- K1: per-block partial sum / sumsq (f64) + zero atomics -----
__global__ __launch_bounds__(256) void k_stats(const float* __restrict__ w,
                                               void* __restrict__ wsv) {
    double* sp = (double*)((char*)wsv + WS_SP_OFF);
    int*    gw = (int*)((char*)wsv + WS_G_OFF);
    double* cw = (double*)((char*)wsv + WS_C_OFF);
    __shared__ double s1[256];
    __shared__ double s2[256];
    int tid = threadIdx.x;

    if (blockIdx.x == 0) {
        if (tid < 15) gw[tid] = 0;
        if (tid >= 32 && tid < 37) cw[tid - 32] = 0.0;
    }

    double a = 0.0, b = 0.0;
    for (int i = blockIdx.x * 256 + tid; i < KW_ELEMS; i += NBLK_RED * 256) {
        double v = (double)w[i];
        a += v; b += v * v;
    }
    s1[tid] = a; s2[tid] = b;
    __syncthreads();
    for (int off = 128; off > 0; off >>= 1) {
        if (tid < off) { s1[tid] += s1[tid + off]; s2[tid] += s2[tid + off]; }
        __syncthreads();
    }
    if (tid == 0) { sp[blockIdx.x * 2] = s1[0]; sp[blockIdx.x * 2 + 1] = s2[0]; }
}

// ---------------- K2: Gram counts + c, atomic finals -------------------------
__global__ __launch_bounds__(256) void k_gc(const float* __restrict__ w,
                                            void* __restrict__ wsv) {
    const double* sp = (const double*)((const char*)wsv + WS_SP_OFF);
    int*    gw = (int*)((char*)wsv + WS_G_OFF);
    double* cw = (double*)((char*)wsv + WS_C_OFF);

    __shared__ int    lg[4][15];
    __shared__ double lc[4][5];

    double sw, sw2;
    read_stats(sp, sw, sw2);
    double mean = sw / (double)KW_ELEMS;
    double var  = sw2 / (double)KW_ELEMS - mean * mean;
    float meanf = (float)mean;
    float sigf  = sqrtf((float)var);

    float sh[5];
    #pragma unroll
    for (int m = 0; m < 5; m++) sh[m] = (-1.0f + 0.5f * (float)m) * sigf;

    int g[15]; double c[5];
    #pragma unroll
    for (int t = 0; t < 15; t++) g[t] = 0;
    #pragma unroll
    for (int i = 0; i < 5; i++) c[i] = 0.0;

    for (int idx = blockIdx.x * 256 + threadIdx.x; idx < KW_ELEMS;
         idx += NBLK_RED * 256) {
        float wf = w[idx];
        float base = wf - meanf;
        int s[5];
        #pragma unroll
        for (int m = 0; m < 5; m++) {
            float arg = base + sh[m];
            s[m] = (arg > 0.0f) ? 1 : ((arg < 0.0f) ? -1 : 0);
        }
        int t = 0;
        #pragma unroll
        for (int i = 0; i < 5; i++) {
            #pragma unroll
            for (int j = i; j < 5; j++) { g[t] += s[i] * s[j]; t++; }
            c[i] += (double)s[i] * (double)wf;
        }
    }
    #pragma unroll
    for (int t = 0; t < 15; t++) {
        int v = g[t];
        for (int off = 32; off > 0; off >>= 1) v += __shfl_down(v, off, 64);
        g[t] = v;
    }
    #pragma unroll
    for (int i = 0; i < 5; i++) {
        double v = c[i];
        for (int off = 32; off > 0; off >>= 1) v += __shfl_down(v, off, 64);
        c[i] = v;
    }
    int wave = threadIdx.x >> 6;
    if ((threadIdx.x & 63) == 0) {
        #pragma unroll
        for (int t = 0; t < 15; t++) lg[wave][t] = g[t];
        #pragma unroll
        for (int i = 0; i < 5; i++) lc[wave][i] = c[i];
    }
    __syncthreads();
    if (threadIdx.x == 0) {
        #pragma unroll
        for (int t = 0; t < 15; t++)
            atomicAdd(&gw[t], lg[0][t] + lg[1][t] + lg[2][t] + lg[3][t]);
        #pragma unroll
        for (int i = 0; i < 5; i++)
            atomicAdd(&cw[i], lc[0][i] + lc[1][i] + lc[2][i] + lc[3][i]);
    }
}

// ---------------- closed-form 500-step GD (1 thread, f64) --------------------
__device__ __forceinline__ void mm5(double* __restrict__ D,
                                    const double* __restrict__ X,
                                    const double* __restrict__ Y) {
    #pragma unroll
    for (int i = 0; i < 5; i++) {
        #pragma unroll
        for (int j = 0; j < 5; j++) {
            double s = 0.0;
            #pragma unroll
            for (int k = 0; k < 5; k++) s += X[i * 5 + k] * Y[k * 5 + j];
            D[i * 5 + j] = s;
        }
    }
}

__device__ void compute_alphas(const int* gw, const double* cw,
                               const float* a0f, float* alph_out) {
    double G[25], C[5];
    {
        int t = 0;
        #pragma unroll
        for (int i = 0; i < 5; i++) {
            #pragma unroll
            for (int j = i; j < 5; j++) {
                double v = (double)gw[t] / (double)KW_ELEMS; t++;
                G[i * 5 + j] = v; G[j * 5 + i] = v;
            }
        }
    }
    #pragma unroll
    for (int i = 0; i < 5; i++) C[i] = cw[i] / (double)KW_ELEMS;

    double L[25];
    #pragma unroll
    for (int i = 0; i < 25; i++) L[i] = 0.0;
    #pragma unroll
    for (int i = 0; i < 5; i++) {
        #pragma unroll
        for (int j = 0; j <= i; j++) {
            double s = G[i * 5 + j];
            #pragma unroll
            for (int k = 0; k < j; k++) s -= L[i * 5 + k] * L[j * 5 + k];
            if (i == j) L[i * 5 + j] = sqrt(s);
            else        L[i * 5 + j] = s / L[j * 5 + j];
        }
    }
    double y[5], astar[5];
    #pragma unroll
    for (int i = 0; i < 5; i++) {
        double s = C[i];
        #pragma unroll
        for (int k = 0; k < i; k++) s -= L[i * 5 + k] * y[k];
        y[i] = s / L[i * 5 + i];
    }
    #pragma unroll
    for (int ii = 0; ii < 5; ii++) {
        int i = 4 - ii;
        double s = y[i];
        #pragma unroll
        for (int k = 0; k < 5; k++) if (k > i) s -= L[k * 5 + i] * astar[k];
        astar[i] = s / L[i * 5 + i];
    }
    double A[25], R[25], T[25];
    #pragma unroll
    for (int i = 0; i < 25; i++) A[i] = ((i % 6) == 0 ? 1.0 : 0.0) - LR_GD * G[i];
    #pragma unroll
    for (int i = 0; i < 25; i++) R[i] = A[i];
    const int bits[8] = {1, 1, 1, 1, 0, 1, 0, 0};   // 500, square-and-multiply
    for (int s = 0; s < 8; s++) {
        mm5(T, R, R);
        if (bits[s]) { mm5(R, T, A); }
        else {
            #pragma unroll
            for (int i = 0; i < 25; i++) R[i] = T[i];
        }
    }
    double d0[5];
    #pragma unroll
    for (int i = 0; i < 5; i++) d0[i] = (double)a0f[i] - astar[i];
    #pragma unroll
    for (int i = 0; i < 5; i++) {
        double s = astar[i];
        #pragma unroll
        for (int j = 0; j < 5; j++) s += R[i * 5 + j] * d0[j];
        alph_out[i] = (float)s;
    }
}

// ---------------- K3: W2[tap][cin32][kg][cout][8] bf16 -----------------------
// grid 144 = tap(9) x cin-quarter(4) x cout-quarter(4).
__global__ __launch_bounds__(256) void k_weff(const float* __restrict__ w,
                                              const float* __restrict__ a0f,
                                              void* __restrict__ wsv) {
    const double* sp = (const double*)((const char*)wsv + WS_SP_OFF);
    const int*    gw = (const int*)((const char*)wsv + WS_G_OFF);
    const double* cw = (const double*)((const char*)wsv + WS_C_OFF);
    unsigned short* wpk = (unsigned short*)((char*)wsv + WS_WP_OFF);

    __shared__ float alph[5];
    __shared__ float tile[32][64];

    int tid   = threadIdx.x;
    int tap   = blockIdx.x >> 4;
    int rest  = blockIdx.x & 15;
    int c32   = rest >> 2;          // cin 32-block index
    int cin0  = c32 * 32;
    int cout0 = (rest & 3) * 64;

    // phase A: issue tile loads — in flight during solve
    int i0 = tid, i1 = tid + 256;
    int ci0 = i0 >> 4, f40 = i0 & 15;
    int ci1 = i1 >> 4, f41 = i1 & 15;
    float4 v0 = *(const float4*)(&w[(tap * 128 + cin0 + ci0) * 256 + cout0 + f40 * 4]);
    float4 v1 = *(const float4*)(&w[(tap * 128 + cin0 + ci1) * 256 + cout0 + f41 * 4]);

    double sw, sw2;
    read_stats(sp, sw, sw2);
    double mean = sw / (double)KW_ELEMS;
    double var  = sw2 / (double)KW_ELEMS - mean * mean;
    float meanf = (float)mean;
    float sigf  = sqrtf((float)var);

    // phase B: serial solve on thread 0 (input = one 20-load burst)
    if (tid == 0) compute_alphas(gw, cw, a0f, alph);
    __syncthreads();

    float al[5] = {alph[0], alph[1], alph[2], alph[3], alph[4]};

    // phase C: combine + LDS transpose + bf16 pack
    {
        float r[4] = {v0.x, v0.y, v0.z, v0.w};
        #pragma unroll
        for (int j = 0; j < 4; j++) {
            float base = r[j] - meanf;
            float acc = 0.0f;
            #pragma unroll
            for (int m = 0; m < 5; m++) {
                float arg = base + (-1.0f + 0.5f * (float)m) * sigf;
                float s = (arg > 0.0f) ? 1.0f : ((arg < 0.0f) ? -1.0f : 0.0f);
                acc += al[m] * s;
            }
            tile[ci0][f40 * 4 + j] = acc;
        }
        float r1[4] = {v1.x, v1.y, v1.z, v1.w};
        #pragma unroll
        for (int j = 0; j < 4; j++) {
            float base = r1[j] - meanf;
            float acc = 0.0f;
            #pragma unroll
            for (int m = 0; m < 5; m++) {
                float arg = base + (-1.0f + 0.5f * (float)m) * sigf;
                float s = (arg > 0.0f) ? 1.0f : ((arg < 0.0f) ? -1.0f : 0.0f);
                acc += al[m] * s;
            }
            tile[ci1][f41 * 4 + j] = acc;
        }
    }
    __syncthreads();

    // writer: thread -> (kg = tid>>6, cout = cout0 + (tid&63));
    // W2 index = ((tap*16 + c32*4 + kg)*256 + cout) * 8
    int cc  = tid & 63;
    int kg  = tid >> 6;          // 8-cin chunk within the 32-block
    unsigned short ob[8];
    #pragma unroll
    for (int k = 0; k < 8; k++) ob[k] = f2bf(tile[kg * 8 + k][cc]);
    unsigned short* dst = wpk + (((tap * 16 + c32 * 4 + kg) * 256) + cout0 + cc) * 8;
    *(short8*)dst = *(short8*)ob;
}

// ---------------- K4: fused binarize-x + 3x3 conv via bf16 MFMA --------------
// sign(clip(x+s,0,1)-0.5) == sign((x+s)-0.5) exactly (clip is monotone, exact
// at 0.5; tie -> 0 preserved), so binarize is one compare pair per branch.
__device__ __forceinline__ float xeff_one(float xv, float s0, float s1, float s2,
                                          float be0, float be1, float be2) {
    float v0 = xv + s0, v1 = xv + s1, v2 = xv + s2;
    float g0 = (v0 > 0.5f) ? 1.0f : ((v0 < 0.5f) ? -1.0f : 0.0f);
    float g1 = (v1 > 0.5f) ? 1.0f : ((v1 < 0.5f) ? -1.0f : 0.0f);
    float g2 = (v2 > 0.5f) ? 1.0f : ((v2 < 0.5f) ? -1.0f : 0.0f);
    return be0 * g0 + be1 * g1 + be2 * g2;
}

// grid 512 = b(8) x h(32) x cout-half(2); 256 thr = 4 waves.
__global__ __launch_bounds__(256, 2) void k_conv(
    const float* __restrict__ x, const float* __restrict__ shiftp,
    const float* __restrict__ beta, const void* __restrict__ wsv,
    float* __restrict__ out) {
    const unsigned short* wp = (const unsigned short*)((const char*)wsv + WS_WP_OFF);
    __shared__ __align__(16) unsigned short ldsx[3 * 34 * 128];   // 26112 B

    int bid = blockIdx.x;
    int ch  = bid & 1;
    int h   = (bid >> 1) & 31;
    int b   = bid >> 6;
    int tid = threadIdx.x;

    float s0 = shiftp[0], s1 = shiftp[1], s2 = shiftp[2];
    float be0 = beta[0], be1 = beta[1], be2 = beta[2];

    // stage X_eff (bf16) rows h-1..h+1, positions -1..32, XOR-swizzled
    for (int i = tid; i < 3 * 34 * 16; i += 256) {
        int cb   = i & 15;
        int pos  = (i >> 4) % 34;
        int drow = (i >> 4) / 34;
        int r  = h - 1 + drow;
        int wpos = pos - 1;
        unsigned short v[8] = {0, 0, 0, 0, 0, 0, 0, 0};
        if (r >= 0 && r < 32 && wpos >= 0 && wpos < 32) {
            const float* xp = &x[(((b * 32 + r) * 32) + wpos) * 128 + cb * 8];
            float4 x0 = *(const float4*)(xp);
            float4 x1 = *(const float4*)(xp + 4);
            float e[8] = {x0.x, x0.y, x0.z, x0.w, x1.x, x1.y, x1.z, x1.w};
            #pragma unroll
            for (int j = 0; j < 8; j++)
                v[j] = f2bf(xeff_one(e[j], s0, s1, s2, be0, be1, be2));
        }
        int row = drow * 34 + pos;
        int byteoff = row * 256 + ((cb * 16) ^ ((row & 7) << 4));
        *(short8*)((char*)ldsx + byteoff) = *(short8*)v;
    }
    __syncthreads();

    int lane = tid & 63;
    int wave = tid >> 6;
    int l15  = lane & 15;
    int kg   = lane >> 4;
    int coutbase = (ch << 7) + wave * 32;

    f32x4 acc[2][2];
    #pragma unroll
    for (int mt = 0; mt < 2; mt++)
        #pragma unroll
        for (int nt = 0; nt < 2; nt++) acc[mt][nt] = (f32x4){0.f, 0.f, 0.f, 0.f};

    #pragma unroll
    for (int dh = 0; dh < 3; dh++) {
        #pragma unroll
        for (int dw = 0; dw < 3; dw++) {
            int tap = dh * 3 + dw;
            int r0 = dh * 34 + l15 + dw;
            int r1 = r0 + 16;
            // coalesced: lanes read consecutive 16B chunks within [kg][cout]
            const unsigned short* wb =
                wp + (((tap * 16 + kg) * 256) + coutbase + l15) * 8;
            #pragma unroll
            for (int c0 = 0; c0 < 128; c0 += 32) {
                int cbyte = c0 * 2 + kg * 16;
                short8 a0f8 = *(const short8*)((const char*)ldsx +
                               (r0 * 256 + (cbyte ^ ((r0 & 7) << 4))));
                short8 a1f8 = *(const short8*)((const char*)ldsx +
                               (r1 * 256 + (cbyte ^ ((r1 & 7) << 4))));
                const unsigned short* wc = wb + (c0 >> 5) * 8192;
                short8 b0f8 = *(const short8*)(wc);
                short8 b1f8 = *(const short8*)(wc + 16 * 8);
                acc[0][0] = __builtin_amdgcn_mfma_f32_16x16x32_bf16(a0f8, b0f8, acc[0][0], 0, 0, 0);
                acc[0][1] = __builtin_amdgcn_mfma_f32_16x16x32_bf16(a0f8, b1f8, acc[0][1], 0, 0, 0);
                acc[1][0] = __builtin_amdgcn_mfma_f32_16x16x32_bf16(a1f8, b0f8, acc[1][0], 0, 0, 0);
                acc[1][1] = __builtin_amdgcn_mfma_f32_16x16x32_bf16(a1f8, b1f8, acc[1][1], 0, 0, 0);
            }
        }
    }

    // D: col = lane&15 (cout), row = kg*4 + reg (pos within 16-tile)
    #pragma unroll
    for (int mt = 0; mt < 2; mt++) {
        #pragma unroll
        for (int nt = 0; nt < 2; nt++) {
            int col = coutbase + nt * 16 + l15;
            #pragma unroll
            for (int reg = 0; reg < 4; reg++) {
                int row = mt * 16 + kg * 4 + reg;
                out[(((b * 32 + h) * 32) + row) * 256 + col] = acc[mt][nt][reg];
            }
        }
    }
}

extern "C" void kernel_launch(void* const* d_in, const int* in_sizes, int n_in,
                              void* d_out, int out_size, void* d_ws, size_t ws_size,
                              hipStream_t stream) {
    const float* x      = (const float*)d_in[0];
    const float* w      = (const float*)d_in[1];
    const float* shiftp = (const float*)d_in[2];
    const float* beta   = (const float*)d_in[3];
    const float* a0     = (const float*)d_in[4];
    float* out = (float*)d_out;

    k_stats<<<NBLK_RED, 256, 0, stream>>>(w, d_ws);
    k_gc<<<NBLK_RED, 256, 0, stream>>>(w, d_ws);
    k_weff<<<144, 256, 0, stream>>>(w, a0, d_ws);
    k_conv<<<512, 256, 0, stream>>>(x, shiftp, beta, d_ws, out);
}

// Round 9
// 54.474 us; speedup vs baseline: 3.0307x; 1.0708x over previous
//
#include <hip/hip_runtime.h>
#include <math.h>

#define KW_ELEMS 294912   // 3*3*128*256
#define LR_GD 0.01
#define NBLK_RED 64       // partial-reduction blocks

typedef __attribute__((ext_vector_type(8))) short short8;
typedef __attribute__((ext_vector_type(4))) float f32x4;

// ws layout (bytes):
//   0     : double stats_parts[64][2]      (sum, sumsq)   1024 B
//   1024  : int    Gint[15]   (atomic finals)               60 B
//   1088  : double c5[5]      (atomic finals)               40 B
//   1152  : ushort W2[9][4][4][256][8]   (bf16, [tap][cin32][kg][cout][cin8])
#define WS_SP_OFF    0
#define WS_G_OFF     1024
#define WS_C_OFF     1088
#define WS_WP_OFF    1152

__device__ __forceinline__ unsigned short f2bf(float f) {
    union { float f; unsigned int u; } v; v.f = f;
    unsigned int r = v.u + 0x7fffu + ((v.u >> 16) & 1u);   // RNE
    return (unsigned short)(r >> 16);
}

// lane-parallel read of the 128 stats partials + butterfly reduce.
__device__ __forceinline__ void read_stats(const double* sp, double& sw, double& sw2) {
    int lane = threadIdx.x & 63;
    double a = sp[2 * lane];
    double b = sp[2 * lane + 1];
    #pragma unroll
    for (int off = 32; off > 0; off >>= 1) {
        a += __shfl_xor(a, off, 64);
        b += __shfl_xor(b, off, 64);
    }
    sw = a; sw2 = b;
}

// ---------------- K1: per-block partial sum / sumsq (f64) + zero atomics -----
__global__ __launch_bounds__(256) void k_stats(const float* __restrict__ w,
                                               void* __restrict__ wsv) {
    double* sp = (double*)((char*)wsv + WS_SP_OFF);
    int*    gw = (int*)((char*)wsv + WS_G_OFF);
    double* cw = (double*)((char*)wsv + WS_C_OFF);
    __shared__ double s1[256];
    __shared__ double s2[256];
    int tid = threadIdx.x;

    if (blockIdx.x == 0) {
        if (tid < 15) gw[tid] = 0;
        if (tid >= 32 && tid < 37) cw[tid - 32] = 0.0;
    }

    double a = 0.0, b = 0.0;
    for (int i = blockIdx.x * 256 + tid; i < KW_ELEMS; i += NBLK_RED * 256) {
        double v = (double)w[i];
        a += v; b += v * v;
    }
    s1[tid] = a; s2[tid] = b;
    __syncthreads();
    for (int off = 128; off > 0; off >>= 1) {
        if (tid < off) { s1[tid] += s1[tid + off]; s2[tid] += s2[tid + off]; }
        __syncthreads();
    }
    if (tid == 0) { sp[blockIdx.x * 2] = s1[0]; sp[blockIdx.x * 2 + 1] = s2[0]; }
}

// ---------------- K2: Gram counts + c, atomic finals -------------------------
__global__ __launch_bounds__(256) void k_gc(const float* __restrict__ w,
                                            void* __restrict__ wsv) {
    const double* sp = (const double*)((const char*)wsv + WS_SP_OFF);
    int*    gw = (int*)((char*)wsv + WS_G_OFF);
    double* cw = (double*)((char*)wsv + WS_C_OFF);

    __shared__ int    lg[4][15];
    __shared__ double lc[4][5];

    double sw, sw2;
    read_stats(sp, sw, sw2);
    double mean = sw / (double)KW_ELEMS;
    double var  = sw2 / (double)KW_ELEMS - mean * mean;
    float meanf = (float)mean;
    float sigf  = sqrtf((float)var);

    float sh[5];
    #pragma unroll
    for (int m = 0; m < 5; m++) sh[m] = (-1.0f + 0.5f * (float)m) * sigf;

    int g[15]; double c[5];
    #pragma unroll
    for (int t = 0; t < 15; t++) g[t] = 0;
    #pragma unroll
    for (int i = 0; i < 5; i++) c[i] = 0.0;

    for (int idx = blockIdx.x * 256 + threadIdx.x; idx < KW_ELEMS;
         idx += NBLK_RED * 256) {
        float wf = w[idx];
        float base = wf - meanf;
        int s[5];
        #pragma unroll
        for (int m = 0; m < 5; m++) {
            float arg = base + sh[m];
            s[m] = (arg > 0.0f) ? 1 : ((arg < 0.0f) ? -1 : 0);
        }
        int t = 0;
        #pragma unroll
        for (int i = 0; i < 5; i++) {
            #pragma unroll
            for (int j = i; j < 5; j++) { g[t] += s[i] * s[j]; t++; }
            c[i] += (double)s[i] * (double)wf;
        }
    }
    #pragma unroll
    for (int t = 0; t < 15; t++) {
        int v = g[t];
        for (int off = 32; off > 0; off >>= 1) v += __shfl_down(v, off, 64);
        g[t] = v;
    }
    #pragma unroll
    for (int i = 0; i < 5; i++) {
        double v = c[i];
        for (int off = 32; off > 0; off >>= 1) v += __shfl_down(v, off, 64);
        c[i] = v;
    }
    int wave = threadIdx.x >> 6;
    if ((threadIdx.x & 63) == 0) {
        #pragma unroll
        for (int t = 0; t < 15; t++) lg[wave][t] = g[t];
        #pragma unroll
        for (int i = 0; i < 5; i++) lc[wave][i] = c[i];
    }
    __syncthreads();
    if (threadIdx.x == 0) {
        #pragma unroll
        for (int t = 0; t < 15; t++)
            atomicAdd(&gw[t], lg[0][t] + lg[1][t] + lg[2][t] + lg[3][t]);
        #pragma unroll
        for (int i = 0; i < 5; i++)
            atomicAdd(&cw[i], lc[0][i] + lc[1][i] + lc[2][i] + lc[3][i]);
    }
}

// ---------------- closed-form 500-step GD (1 thread, f64) --------------------
__device__ __forceinline__ void mm5(double* __restrict__ D,
                                    const double* __restrict__ X,
                                    const double* __restrict__ Y) {
    #pragma unroll
    for (int i = 0; i < 5; i++) {
        #pragma unroll
        for (int j = 0; j < 5; j++) {
            double s = 0.0;
            #pragma unroll
            for (int k = 0; k < 5; k++) s += X[i * 5 + k] * Y[k * 5 + j];
            D[i * 5 + j] = s;
        }
    }
}

__device__ void compute_alphas(const int* gw, const double* cw,
                               const float* a0f, float* alph_out) {
    double G[25], C[5];
    {
        int t = 0;
        #pragma unroll
        for (int i = 0; i < 5; i++) {
            #pragma unroll
            for (int j = i; j < 5; j++) {
                double v = (double)gw[t] / (double)KW_ELEMS; t++;
                G[i * 5 + j] = v; G[j * 5 + i] = v;
            }
        }
    }
    #pragma unroll
    for (int i = 0; i < 5; i++) C[i] = cw[i] / (double)KW_ELEMS;

    double L[25];
    #pragma unroll
    for (int i = 0; i < 25; i++) L[i] = 0.0;
    #pragma unroll
    for (int i = 0; i < 5; i++) {
        #pragma unroll
        for (int j = 0; j <= i; j++) {
            double s = G[i * 5 + j];
            #pragma unroll
            for (int k = 0; k < j; k++) s -= L[i * 5 + k] * L[j * 5 + k];
            if (i == j) L[i * 5 + j] = sqrt(s);
            else        L[i * 5 + j] = s / L[j * 5 + j];
        }
    }
    double y[5], astar[5];
    #pragma unroll
    for (int i = 0; i < 5; i++) {
        double s = C[i];
        #pragma unroll
        for (int k = 0; k < i; k++) s -= L[i * 5 + k] * y[k];
        y[i] = s / L[i * 5 + i];
    }
    #pragma unroll
    for (int ii = 0; ii < 5; ii++) {
        int i = 4 - ii;
        double s = y[i];
        #pragma unroll
        for (int k = 0; k < 5; k++) if (k > i) s -= L[k * 5 + i] * astar[k];
        astar[i] = s / L[i * 5 + i];
    }
    double A[25], R[25], T[25];
    #pragma unroll
    for (int i = 0; i < 25; i++) A[i] = ((i % 6) == 0 ? 1.0 : 0.0) - LR_GD * G[i];
    #pragma unroll
    for (int i = 0; i < 25; i++) R[i] = A[i];
    const int bits[8] = {1, 1, 1, 1, 0, 1, 0, 0};   // 500, square-and-multiply
    for (int s = 0; s < 8; s++) {
        mm5(T, R, R);
        if (bits[s]) { mm5(R, T, A); }
        else {
            #pragma unroll
            for (int i = 0; i < 25; i++) R[i] = T[i];
        }
    }
    double d0[5];
    #pragma unroll
    for (int i = 0; i < 5; i++) d0[i] = (double)a0f[i] - astar[i];
    #pragma unroll
    for (int i = 0; i < 5; i++) {
        double s = astar[i];
        #pragma unroll
        for (int j = 0; j < 5; j++) s += R[i * 5 + j] * d0[j];
        alph_out[i] = (float)s;
    }
}

// ---------------- K3: W2[tap][cin32][kg][cout][8] bf16 -----------------------
// grid 144 = tap(9) x cin-quarter(4) x cout-quarter(4).
__global__ __launch_bounds__(256) void k_weff(const float* __restrict__ w,
                                              const float* __restrict__ a0f,
                                              void* __restrict__ wsv) {
    const double* sp = (const double*)((const char*)wsv + WS_SP_OFF);
    const int*    gw = (const int*)((const char*)wsv + WS_G_OFF);
    const double* cw = (const double*)((const char*)wsv + WS_C_OFF);
    unsigned short* wpk = (unsigned short*)((char*)wsv + WS_WP_OFF);

    __shared__ float alph[5];
    __shared__ float tile[32][64];

    int tid   = threadIdx.x;
    int tap   = blockIdx.x >> 4;
    int rest  = blockIdx.x & 15;
    int c32   = rest >> 2;          // cin 32-block index
    int cin0  = c32 * 32;
    int cout0 = (rest & 3) * 64;

    // phase A: issue tile loads — in flight during solve
    int i0 = tid, i1 = tid + 256;
    int ci0 = i0 >> 4, f40 = i0 & 15;
    int ci1 = i1 >> 4, f41 = i1 & 15;
    float4 v0 = *(const float4*)(&w[(tap * 128 + cin0 + ci0) * 256 + cout0 + f40 * 4]);
    float4 v1 = *(const float4*)(&w[(tap * 128 + cin0 + ci1) * 256 + cout0 + f41 * 4]);

    double sw, sw2;
    read_stats(sp, sw, sw2);
    double mean = sw / (double)KW_ELEMS;
    double var  = sw2 / (double)KW_ELEMS - mean * mean;
    float meanf = (float)mean;
    float sigf  = sqrtf((float)var);

    // phase B: serial solve on thread 0 (input = one 20-load burst)
    if (tid == 0) compute_alphas(gw, cw, a0f, alph);
    __syncthreads();

    float al[5] = {alph[0], alph[1], alph[2], alph[3], alph[4]};

    // phase C: combine + LDS transpose + bf16 pack
    {
        float r[4] = {v0.x, v0.y, v0.z, v0.w};
        #pragma unroll
        for (int j = 0; j < 4; j++) {
            float base = r[j] - meanf;
            float acc = 0.0f;
            #pragma unroll
            for (int m = 0; m < 5; m++) {
                float arg = base + (-1.0f + 0.5f * (float)m) * sigf;
                float s = (arg > 0.0f) ? 1.0f : ((arg < 0.0f) ? -1.0f : 0.0f);
                acc += al[m] * s;
            }
            tile[ci0][f40 * 4 + j] = acc;
        }
        float r1[4] = {v1.x, v1.y, v1.z, v1.w};
        #pragma unroll
        for (int j = 0; j < 4; j++) {
            float base = r1[j] - meanf;
            float acc = 0.0f;
            #pragma unroll
            for (int m = 0; m < 5; m++) {
                float arg = base + (-1.0f + 0.5f * (float)m) * sigf;
                float s = (arg > 0.0f) ? 1.0f : ((arg < 0.0f) ? -1.0f : 0.0f);
                acc += al[m] * s;
            }
            tile[ci1][f41 * 4 + j] = acc;
        }
    }
    __syncthreads();

    int cc  = tid & 63;
    int kg  = tid >> 6;          // 8-cin chunk within the 32-block
    unsigned short ob[8];
    #pragma unroll
    for (int k = 0; k < 8; k++) ob[k] = f2bf(tile[kg * 8 + k][cc]);
    unsigned short* dst = wpk + (((tap * 16 + c32 * 4 + kg) * 256) + cout0 + cc) * 8;
    *(short8*)dst = *(short8*)ob;
}

// ---------------- K4: fused binarize-x + 3x3 conv via bf16 MFMA --------------
// sign(clip(x+s,0,1)-0.5) == sign((x+s)-0.5) exactly.
__device__ __forceinline__ float xeff_one(float xv, float s0, float s1, float s2,
                                          float be0, float be1, float be2) {
    float v0 = xv + s0, v1 = xv + s1, v2 = xv + s2;
    float g0 = (v0 > 0.5f) ? 1.0f : ((v0 < 0.5f) ? -1.0f : 0.0f);
    float g1 = (v1 > 0.5f) ? 1.0f : ((v1 < 0.5f) ? -1.0f : 0.0f);
    float g2 = (v2 > 0.5f) ? 1.0f : ((v2 < 0.5f) ? -1.0f : 0.0f);
    return be0 * g0 + be1 * g1 + be2 * g2;
}

// grid 512 = b(8) x h(32) x cout-half(2); 256 thr = 4 waves.
// B-fragments double-buffered one tap ahead (T14 issue-early/consume-late).
__global__ __launch_bounds__(256, 2) void k_conv(
    const float* __restrict__ x, const float* __restrict__ shiftp,
    const float* __restrict__ beta, const void* __restrict__ wsv,
    float* __restrict__ out) {
    const unsigned short* wp = (const unsigned short*)((const char*)wsv + WS_WP_OFF);
    __shared__ __align__(16) unsigned short ldsx[3 * 34 * 128];   // 26112 B

    int bid = blockIdx.x;
    int ch  = bid & 1;
    int h   = (bid >> 1) & 31;
    int b   = bid >> 6;
    int tid = threadIdx.x;

    float s0 = shiftp[0], s1 = shiftp[1], s2 = shiftp[2];
    float be0 = beta[0], be1 = beta[1], be2 = beta[2];

    // stage X_eff (bf16) rows h-1..h+1, positions -1..32, XOR-swizzled
    for (int i = tid; i < 3 * 34 * 16; i += 256) {
        int cb   = i & 15;
        int pos  = (i >> 4) % 34;
        int drow = (i >> 4) / 34;
        int r  = h - 1 + drow;
        int wpos = pos - 1;
        unsigned short v[8] = {0, 0, 0, 0, 0, 0, 0, 0};
        if (r >= 0 && r < 32 && wpos >= 0 && wpos < 32) {
            const float* xp = &x[(((b * 32 + r) * 32) + wpos) * 128 + cb * 8];
            float4 x0 = *(const float4*)(xp);
            float4 x1 = *(const float4*)(xp + 4);
            float e[8] = {x0.x, x0.y, x0.z, x0.w, x1.x, x1.y, x1.z, x1.w};
            #pragma unroll
            for (int j = 0; j < 8; j++)
                v[j] = f2bf(xeff_one(e[j], s0, s1, s2, be0, be1, be2));
        }
        int row = drow * 34 + pos;
        int byteoff = row * 256 + ((cb * 16) ^ ((row & 7) << 4));
        *(short8*)((char*)ldsx + byteoff) = *(short8*)v;
    }
    __syncthreads();

    int lane = tid & 63;
    int wave = tid >> 6;
    int l15  = lane & 15;
    int kg   = lane >> 4;
    int coutbase = (ch << 7) + wave * 32;

    f32x4 acc[2][2];
    #pragma unroll
    for (int mt = 0; mt < 2; mt++)
        #pragma unroll
        for (int nt = 0; nt < 2; nt++) acc[mt][nt] = (f32x4){0.f, 0.f, 0.f, 0.f};

    // per-lane weight base; tap stride = 16*256*8 = 32768 ushorts,
    // chunk stride = 256*8 = 2048*4 = 8192 ushorts, nt stride = 16*8 = 128.
    const unsigned short* wbase = wp + ((kg * 256) + coutbase + l15) * 8;

    short8 bc[8], bn[8];
    #pragma unroll
    for (int q = 0; q < 4; q++) {
        bc[2 * q]     = *(const short8*)(wbase + q * 8192);
        bc[2 * q + 1] = *(const short8*)(wbase + q * 8192 + 128);
    }

    #pragma unroll
    for (int dh = 0; dh < 3; dh++) {
        #pragma unroll
        for (int dw = 0; dw < 3; dw++) {
            int tap = dh * 3 + dw;
            // issue next tap's 8 B-loads first (stay in flight under MFMA)
            if (tap < 8) {
                const unsigned short* wnx = wbase + (tap + 1) * 32768;
                #pragma unroll
                for (int q = 0; q < 4; q++) {
                    bn[2 * q]     = *(const short8*)(wnx + q * 8192);
                    bn[2 * q + 1] = *(const short8*)(wnx + q * 8192 + 128);
                }
            }
            int r0 = dh * 34 + l15 + dw;
            int r1 = r0 + 16;
            #pragma unroll
            for (int q = 0; q < 4; q++) {
                int cbyte = q * 64 + kg * 16;
                short8 a0f8 = *(const short8*)((const char*)ldsx +
                               (r0 * 256 + (cbyte ^ ((r0 & 7) << 4))));
                short8 a1f8 = *(const short8*)((const char*)ldsx +
                               (r1 * 256 + (cbyte ^ ((r1 & 7) << 4))));
                acc[0][0] = __builtin_amdgcn_mfma_f32_16x16x32_bf16(a0f8, bc[2*q],   acc[0][0], 0, 0, 0);
                acc[0][1] = __builtin_amdgcn_mfma_f32_16x16x32_bf16(a0f8, bc[2*q+1], acc[0][1], 0, 0, 0);
                acc[1][0] = __builtin_amdgcn_mfma_f32_16x16x32_bf16(a1f8, bc[2*q],   acc[1][0], 0, 0, 0);
                acc[1][1] = __builtin_amdgcn_mfma_f32_16x16x32_bf16(a1f8, bc[2*q+1], acc[1][1], 0, 0, 0);
            }
            if (tap < 8) {
                #pragma unroll
                for (int i = 0; i < 8; i++) bc[i] = bn[i];
            }
        }
    }

    // D: col = lane&15 (cout), row = kg*4 + reg (pos within 16-tile)
    #pragma unroll
    for (int mt = 0; mt < 2; mt++) {
        #pragma unroll
        for (int nt = 0; nt < 2; nt++) {
            int col = coutbase + nt * 16 + l15;
            #pragma unroll
            for (int reg = 0; reg < 4; reg++) {
                int row = mt * 16 + kg * 4 + reg;
                out[(((b * 32 + h) * 32) + row) * 256 + col] = acc[mt][nt][reg];
            }
        }
    }
}

extern "C" void kernel_launch(void* const* d_in, const int* in_sizes, int n_in,
                              void* d_out, int out_size, void* d_ws, size_t ws_size,
                              hipStream_t stream) {
    const float* x      = (const float*)d_in[0];
    const float* w      = (const float*)d_in[1];
    const float* shiftp = (const float*)d_in[2];
    const float* beta   = (const float*)d_in[3];
    const float* a0     = (const float*)d_in[4];
    float* out = (float*)d_out;

    k_stats<<<NBLK_RED, 256, 0, stream>>>(w, d_ws);
    k_gc<<<NBLK_RED, 256, 0, stream>>>(w, d_ws);
    k_weff<<<144, 256, 0, stream>>>(w, a0, d_ws);
    k_conv<<<512, 256, 0, stream>>>(x, shiftp, beta, d_ws, out);
}

// Round 10
// 51.240 us; speedup vs baseline: 3.2220x; 1.0631x over previous
//
#include <hip/hip_runtime.h>
#include <math.h>

#define KW_ELEMS 294912   // 3*3*128*256
#define LR_GD 0.01
#define NBLK_RED 64       // partial-reduction blocks

typedef __attribute__((ext_vector_type(8))) short short8;
typedef __attribute__((ext_vector_type(4))) float f32x4;

// ws layout (bytes):
//   0     : double stats_parts[64][2]      (sum, sumsq)   1024 B
//   1024  : int    Gint[15]   (atomic finals)               60 B
//   1088  : double c5[5]      (atomic finals)               40 B
//   1152  : ushort W2[9][4][4][256][8]   (bf16, [tap][cin32][kg][cout][cin8])
#define WS_SP_OFF    0
#define WS_G_OFF     1024
#define WS_C_OFF     1088
#define WS_WP_OFF    1152

__device__ __forceinline__ unsigned short f2bf(float f) {
    union { float f; unsigned int u; } v; v.f = f;
    unsigned int r = v.u + 0x7fffu + ((v.u >> 16) & 1u);   // RNE
    return (unsigned short)(r >> 16);
}

// lane-parallel read of the 128 stats partials + butterfly reduce.
__device__ __forceinline__ void read_stats(const double* sp, double& sw, double& sw2) {
    int lane = threadIdx.x & 63;
    double a = sp[2 * lane];
    double b = sp[2 * lane + 1];
    #pragma unroll
    for (int off = 32; off > 0; off >>= 1) {
        a += __shfl_xor(a, off, 64);
        b += __shfl_xor(b, off, 64);
    }
    sw = a; sw2 = b;
}

// ---------------- K1: per-block partial sum / sumsq (f64) + zero atomics -----
__global__ __launch_bounds__(256) void k_stats(const float* __restrict__ w,
                                               void* __restrict__ wsv) {
    double* sp = (double*)((char*)wsv + WS_SP_OFF);
    int*    gw = (int*)((char*)wsv + WS_G_OFF);
    double* cw = (double*)((char*)wsv + WS_C_OFF);
    __shared__ double s1[256];
    __shared__ double s2[256];
    int tid = threadIdx.x;

    if (blockIdx.x == 0) {
        if (tid < 15) gw[tid] = 0;
        if (tid >= 32 && tid < 37) cw[tid - 32] = 0.0;
    }

    double a = 0.0, b = 0.0;
    for (int i = blockIdx.x * 256 + tid; i < KW_ELEMS; i += NBLK_RED * 256) {
        double v = (double)w[i];
        a += v; b += v * v;
    }
    s1[tid] = a; s2[tid] = b;
    __syncthreads();
    for (int off = 128; off > 0; off >>= 1) {
        if (tid < off) { s1[tid] += s1[tid + off]; s2[tid] += s2[tid + off]; }
        __syncthreads();
    }
    if (tid == 0) { sp[blockIdx.x * 2] = s1[0]; sp[blockIdx.x * 2 + 1] = s2[0]; }
}

// ---------------- K2: Gram counts + c, atomic finals -------------------------
__global__ __launch_bounds__(256) void k_gc(const float* __restrict__ w,
                                            void* __restrict__ wsv) {
    const double* sp = (const double*)((const char*)wsv + WS_SP_OFF);
    int*    gw = (int*)((char*)wsv + WS_G_OFF);
    double* cw = (double*)((char*)wsv + WS_C_OFF);

    __shared__ int    lg[4][15];
    __shared__ double lc[4][5];

    double sw, sw2;
    read_stats(sp, sw, sw2);
    double mean = sw / (double)KW_ELEMS;
    double var  = sw2 / (double)KW_ELEMS - mean * mean;
    float meanf = (float)mean;
    float sigf  = sqrtf((float)var);

    float sh[5];
    #pragma unroll
    for (int m = 0; m < 5; m++) sh[m] = (-1.0f + 0.5f * (float)m) * sigf;

    int g[15]; double c[5];
    #pragma unroll
    for (int t = 0; t < 15; t++) g[t] = 0;
    #pragma unroll
    for (int i = 0; i < 5; i++) c[i] = 0.0;

    for (int idx = blockIdx.x * 256 + threadIdx.x; idx < KW_ELEMS;
         idx += NBLK_RED * 256) {
        float wf = w[idx];
        float base = wf - meanf;
        int s[5];
        #pragma unroll
        for (int m = 0; m < 5; m++) {
            float arg = base + sh[m];
            s[m] = (arg > 0.0f) ? 1 : ((arg < 0.0f) ? -1 : 0);
        }
        int t = 0;
        #pragma unroll
        for (int i = 0; i < 5; i++) {
            #pragma unroll
            for (int j = i; j < 5; j++) { g[t] += s[i] * s[j]; t++; }
            c[i] += (double)s[i] * (double)wf;
        }
    }
    #pragma unroll
    for (int t = 0; t < 15; t++) {
        int v = g[t];
        for (int off = 32; off > 0; off >>= 1) v += __shfl_down(v, off, 64);
        g[t] = v;
    }
    #pragma unroll
    for (int i = 0; i < 5; i++) {
        double v = c[i];
        for (int off = 32; off > 0; off >>= 1) v += __shfl_down(v, off, 64);
        c[i] = v;
    }
    int wave = threadIdx.x >> 6;
    if ((threadIdx.x & 63) == 0) {
        #pragma unroll
        for (int t = 0; t < 15; t++) lg[wave][t] = g[t];
        #pragma unroll
        for (int i = 0; i < 5; i++) lc[wave][i] = c[i];
    }
    __syncthreads();
    if (threadIdx.x == 0) {
        #pragma unroll
        for (int t = 0; t < 15; t++)
            atomicAdd(&gw[t], lg[0][t] + lg[1][t] + lg[2][t] + lg[3][t]);
        #pragma unroll
        for (int i = 0; i < 5; i++)
            atomicAdd(&cw[i], lc[0][i] + lc[1][i] + lc[2][i] + lc[3][i]);
    }
}

// ---------------- K3: W2 pack + lane-parallel closed-form alpha solve --------
// grid 144 = tap(9) x cin-quarter(4) x cout-quarter(4).
// Solve: lanes 0-24 do A^500 via LDS 5x5 matmuls (2 barriers/round);
// lane 64 (wave 1) does Cholesky+triangular solves concurrently.
__global__ __launch_bounds__(256) void k_weff(const float* __restrict__ w,
                                              const float* __restrict__ a0f,
                                              void* __restrict__ wsv) {
    const double* sp = (const double*)((const char*)wsv + WS_SP_OFF);
    const int*    gw = (const int*)((const char*)wsv + WS_G_OFF);
    const double* cw = (const double*)((const char*)wsv + WS_C_OFF);
    unsigned short* wpk = (unsigned short*)((char*)wsv + WS_WP_OFF);

    __shared__ double Gd[25], Am[25], Rm[25], Tm[25];
    __shared__ double astar_s[5];
    __shared__ float  alph[5];
    __shared__ float  tile[32][64];

    int tid   = threadIdx.x;
    int tap   = blockIdx.x >> 4;
    int rest  = blockIdx.x & 15;
    int c32   = rest >> 2;          // cin 32-block index
    int cin0  = c32 * 32;
    int cout0 = (rest & 3) * 64;

    // phase A: issue tile loads — in flight during solve
    int i0 = tid, i1 = tid + 256;
    int ci0 = i0 >> 4, f40 = i0 & 15;
    int ci1 = i1 >> 4, f41 = i1 & 15;
    float4 v0 = *(const float4*)(&w[(tap * 128 + cin0 + ci0) * 256 + cout0 + f40 * 4]);
    float4 v1 = *(const float4*)(&w[(tap * 128 + cin0 + ci1) * 256 + cout0 + f41 * 4]);

    double sw, sw2;
    read_stats(sp, sw, sw2);
    double mean = sw / (double)KW_ELEMS;
    double var  = sw2 / (double)KW_ELEMS - mean * mean;
    float meanf = (float)mean;
    float sigf  = sqrtf((float)var);

    // stage G, A=I-LR*G, R=A into LDS (lanes 0-24)
    if (tid < 25) {
        int i = tid / 5, j = tid % 5;
        int ii = (i < j) ? i : j;
        int jj = (i < j) ? j : i;
        int t = 5 * ii - (ii * (ii - 1)) / 2 + (jj - ii);
        double v = (double)gw[t] / (double)KW_ELEMS;
        Gd[tid] = v;
        double a = ((i == j) ? 1.0 : 0.0) - LR_GD * v;
        Am[tid] = a;
        Rm[tid] = a;
    }
    __syncthreads();

    // wave 1, lane 64: Cholesky + 2 triangular solves (serial, ~100 f64 ops),
    // runs while wave 0 grinds the A^500 rounds below.
    if (tid == 64) {
        double L[25];
        #pragma unroll
        for (int i = 0; i < 25; i++) L[i] = 0.0;
        #pragma unroll
        for (int i = 0; i < 5; i++) {
            #pragma unroll
            for (int j = 0; j <= i; j++) {
                double s = Gd[i * 5 + j];
                #pragma unroll
                for (int k = 0; k < j; k++) s -= L[i * 5 + k] * L[j * 5 + k];
                if (i == j) L[i * 5 + j] = sqrt(s);
                else        L[i * 5 + j] = s / L[j * 5 + j];
            }
        }
        double y[5], astar[5];
        #pragma unroll
        for (int i = 0; i < 5; i++) {
            double s = cw[i] / (double)KW_ELEMS;
            #pragma unroll
            for (int k = 0; k < i; k++) s -= L[i * 5 + k] * y[k];
            y[i] = s / L[i * 5 + i];
        }
        #pragma unroll
        for (int ii2 = 0; ii2 < 5; ii2++) {
            int i = 4 - ii2;
            double s = y[i];
            #pragma unroll
            for (int k = 0; k < 5; k++) if (k > i) s -= L[k * 5 + i] * astar[k];
            astar[i] = s / L[i * 5 + i];
        }
        #pragma unroll
        for (int i = 0; i < 5; i++) astar_s[i] = astar[i];
    }

    // A^500 rounds (500 = square-and-multiply bits 1,1,1,1,0,1,0,0)
    {
        int i = tid / 5, j = tid % 5;
        const int bits[8] = {1, 1, 1, 1, 0, 1, 0, 0};
        #pragma unroll
        for (int s = 0; s < 8; s++) {
            double tv = 0.0;
            if (tid < 25) {
                #pragma unroll
                for (int k = 0; k < 5; k++) tv += Rm[i * 5 + k] * Rm[k * 5 + j];
                Tm[tid] = tv;
            }
            __syncthreads();          // Tm ready; all Rm reads done
            double rv = tv;
            if (tid < 25) {
                if (bits[s]) {
                    rv = 0.0;
                    #pragma unroll
                    for (int k = 0; k < 5; k++) rv += Tm[i * 5 + k] * Am[k * 5 + j];
                }
                Rm[tid] = rv;
            }
            __syncthreads();          // Rm ready for next round
        }
    }

    // alph = astar + R (a0 - astar), lanes 0-4
    if (tid < 5) {
        double s = astar_s[tid];
        #pragma unroll
        for (int j = 0; j < 5; j++)
            s += Rm[tid * 5 + j] * ((double)a0f[j] - astar_s[j]);
        alph[tid] = (float)s;
    }
    __syncthreads();

    float al[5] = {alph[0], alph[1], alph[2], alph[3], alph[4]};

    // phase C: combine + LDS transpose + bf16 pack
    {
        float r[4] = {v0.x, v0.y, v0.z, v0.w};
        #pragma unroll
        for (int j = 0; j < 4; j++) {
            float base = r[j] - meanf;
            float acc = 0.0f;
            #pragma unroll
            for (int m = 0; m < 5; m++) {
                float arg = base + (-1.0f + 0.5f * (float)m) * sigf;
                float s = (arg > 0.0f) ? 1.0f : ((arg < 0.0f) ? -1.0f : 0.0f);
                acc += al[m] * s;
            }
            tile[ci0][f40 * 4 + j] = acc;
        }
        float r1[4] = {v1.x, v1.y, v1.z, v1.w};
        #pragma unroll
        for (int j = 0; j < 4; j++) {
            float base = r1[j] - meanf;
            float acc = 0.0f;
            #pragma unroll
            for (int m = 0; m < 5; m++) {
                float arg = base + (-1.0f + 0.5f * (float)m) * sigf;
                float s = (arg > 0.0f) ? 1.0f : ((arg < 0.0f) ? -1.0f : 0.0f);
                acc += al[m] * s;
            }
            tile[ci1][f41 * 4 + j] = acc;
        }
    }
    __syncthreads();

    int cc  = tid & 63;
    int kg  = tid >> 6;          // 8-cin chunk within the 32-block
    unsigned short ob[8];
    #pragma unroll
    for (int k = 0; k < 8; k++) ob[k] = f2bf(tile[kg * 8 + k][cc]);
    unsigned short* dst = wpk + (((tap * 16 + c32 * 4 + kg) * 256) + cout0 + cc) * 8;
    *(short8*)dst = *(short8*)ob;
}

// ---------------- K4: fused binarize-x + 3x3 conv via bf16 MFMA --------------
// sign(clip(x+s,0,1)-0.5) == sign((x+s)-0.5) exactly.
__device__ __forceinline__ float xeff_one(float xv, float s0, float s1, float s2,
                                          float be0, float be1, float be2) {
    float v0 = xv + s0, v1 = xv + s1, v2 = xv + s2;
    float g0 = (v0 > 0.5f) ? 1.0f : ((v0 < 0.5f) ? -1.0f : 0.0f);
    float g1 = (v1 > 0.5f) ? 1.0f : ((v1 < 0.5f) ? -1.0f : 0.0f);
    float g2 = (v2 > 0.5f) ? 1.0f : ((v2 < 0.5f) ? -1.0f : 0.0f);
    return be0 * g0 + be1 * g1 + be2 * g2;
}

// grid 512 = b(8) x h(32) x cout-half(2); 256 thr = 4 waves.
// B-fragments double-buffered one tap ahead (T14 issue-early/consume-late).
__global__ __launch_bounds__(256, 2) void k_conv(
    const float* __restrict__ x, const float* __restrict__ shiftp,
    const float* __restrict__ beta, const void* __restrict__ wsv,
    float* __restrict__ out) {
    const unsigned short* wp = (const unsigned short*)((const char*)wsv + WS_WP_OFF);
    __shared__ __align__(16) unsigned short ldsx[3 * 34 * 128];   // 26112 B

    int bid = blockIdx.x;
    int ch  = bid & 1;
    int h   = (bid >> 1) & 31;
    int b   = bid >> 6;
    int tid = threadIdx.x;

    float s0 = shiftp[0], s1 = shiftp[1], s2 = shiftp[2];
    float be0 = beta[0], be1 = beta[1], be2 = beta[2];

    // stage X_eff (bf16) rows h-1..h+1, positions -1..32, XOR-swizzled
    for (int i = tid; i < 3 * 34 * 16; i += 256) {
        int cb   = i & 15;
        int pos  = (i >> 4) % 34;
        int drow = (i >> 4) / 34;
        int r  = h - 1 + drow;
        int wpos = pos - 1;
        unsigned short v[8] = {0, 0, 0, 0, 0, 0, 0, 0};
        if (r >= 0 && r < 32 && wpos >= 0 && wpos < 32) {
            const float* xp = &x[(((b * 32 + r) * 32) + wpos) * 128 + cb * 8];
            float4 x0 = *(const float4*)(xp);
            float4 x1 = *(const float4*)(xp + 4);
            float e[8] = {x0.x, x0.y, x0.z, x0.w, x1.x, x1.y, x1.z, x1.w};
            #pragma unroll
            for (int j = 0; j < 8; j++)
                v[j] = f2bf(xeff_one(e[j], s0, s1, s2, be0, be1, be2));
        }
        int row = drow * 34 + pos;
        int byteoff = row * 256 + ((cb * 16) ^ ((row & 7) << 4));
        *(short8*)((char*)ldsx + byteoff) = *(short8*)v;
    }
    __syncthreads();

    int lane = tid & 63;
    int wave = tid >> 6;
    int l15  = lane & 15;
    int kg   = lane >> 4;
    int coutbase = (ch << 7) + wave * 32;

    f32x4 acc[2][2];
    #pragma unroll
    for (int mt = 0; mt < 2; mt++)
        #pragma unroll
        for (int nt = 0; nt < 2; nt++) acc[mt][nt] = (f32x4){0.f, 0.f, 0.f, 0.f};

    // per-lane weight base; tap stride = 16*256*8 = 32768 ushorts,
    // chunk stride = 256*8 = 8192 ushorts, nt stride = 16*8 = 128.
    const unsigned short* wbase = wp + ((kg * 256) + coutbase + l15) * 8;

    short8 bc[8], bn[8];
    #pragma unroll
    for (int q = 0; q < 4; q++) {
        bc[2 * q]     = *(const short8*)(wbase + q * 8192);
        bc[2 * q + 1] = *(const short8*)(wbase + q * 8192 + 128);
    }

    #pragma unroll
    for (int dh = 0; dh < 3; dh++) {
        #pragma unroll
        for (int dw = 0; dw < 3; dw++) {
            int tap = dh * 3 + dw;
            // issue next tap's 8 B-loads first (stay in flight under MFMA)
            if (tap < 8) {
                const unsigned short* wnx = wbase + (tap + 1) * 32768;
                #pragma unroll
                for (int q = 0; q < 4; q++) {
                    bn[2 * q]     = *(const short8*)(wnx + q * 8192);
                    bn[2 * q + 1] = *(const short8*)(wnx + q * 8192 + 128);
                }
            }
            int r0 = dh * 34 + l15 + dw;
            int r1 = r0 + 16;
            #pragma unroll
            for (int q = 0; q < 4; q++) {
                int cbyte = q * 64 + kg * 16;
                short8 a0f8 = *(const short8*)((const char*)ldsx +
                               (r0 * 256 + (cbyte ^ ((r0 & 7) << 4))));
                short8 a1f8 = *(const short8*)((const char*)ldsx +
                               (r1 * 256 + (cbyte ^ ((r1 & 7) << 4))));
                acc[0][0] = __builtin_amdgcn_mfma_f32_16x16x32_bf16(a0f8, bc[2*q],   acc[0][0], 0, 0, 0);
                acc[0][1] = __builtin_amdgcn_mfma_f32_16x16x32_bf16(a0f8, bc[2*q+1], acc[0][1], 0, 0, 0);
                acc[1][0] = __builtin_amdgcn_mfma_f32_16x16x32_bf16(a1f8, bc[2*q],   acc[1][0], 0, 0, 0);
                acc[1][1] = __builtin_amdgcn_mfma_f32_16x16x32_bf16(a1f8, bc[2*q+1], acc[1][1], 0, 0, 0);
            }
            if (tap < 8) {
                #pragma unroll
                for (int i = 0; i < 8; i++) bc[i] = bn[i];
            }
        }
    }

    // D: col = lane&15 (cout), row = kg*4 + reg (pos within 16-tile)
    #pragma unroll
    for (int mt = 0; mt < 2; mt++) {
        #pragma unroll
        for (int nt = 0; nt < 2; nt++) {
            int col = coutbase + nt * 16 + l15;
            #pragma unroll
            for (int reg = 0; reg < 4; reg++) {
                int row = mt * 16 + kg * 4 + reg;
                out[(((b * 32 + h) * 32) + row) * 256 + col] = acc[mt][nt][reg];
            }
        }
    }
}

extern "C" void kernel_launch(void* const* d_in, const int* in_sizes, int n_in,
                              void* d_out, int out_size, void* d_ws, size_t ws_size,
                              hipStream_t stream) {
    const float* x      = (const float*)d_in[0];
    const float* w      = (const float*)d_in[1];
    const float* shiftp = (const float*)d_in[2];
    const float* beta   = (const float*)d_in[3];
    const float* a0     = (const float*)d_in[4];
    float* out = (float*)d_out;

    k_stats<<<NBLK_RED, 256, 0, stream>>>(w, d_ws);
    k_gc<<<NBLK_RED, 256, 0, stream>>>(w, d_ws);
    k_weff<<<144, 256, 0, stream>>>(w, a0, d_ws);
    k_conv<<<512, 256, 0, stream>>>(x, shiftp, beta, d_ws, out);
}